// Round 1
// baseline (1228.057 us; speedup 1.0000x reference)
//
#include <hip/hip_runtime.h>
#include <hip/hip_bf16.h>
#include <math.h>

#define IN_DIM 128
#define HID 128
#define HEADS 8
#define C1 16
#define OUT_DIM 64
#define SLOPE 0.2f

__device__ __forceinline__ float lrelu(float x) { return fmaxf(x, SLOPE * x); }

// ---------------- dtype detection for edge_index (int32 vs int64 storage) ---
__global__ void detect_kernel(const int* __restrict__ idx, int* __restrict__ flag) {
    if (blockIdx.x == 0 && threadIdx.x == 0) {
        int nz = 0;
        for (int i = 1; i < 1024; i += 2) nz += (idx[i] != 0);
        *flag = (nz > 16) ? 1 : 0;   // 1 => int32 storage, 0 => int64 storage
    }
}

// ---------------- GEMM1: h1[N,128] = x[N,128] @ W1[128,128] ------------------
__global__ __launch_bounds__(256) void gemm1_kernel(
    const float* __restrict__ x, const float* __restrict__ W1,
    float* __restrict__ h1, int N) {
    __shared__ float xs[64 * 128];
    int row0 = blockIdx.x * 64;
    int t = threadIdx.x;
    for (int i = t; i < 64 * 128 / 4; i += 256) {
        int r = (i * 4) / 128, c = (i * 4) % 128;
        int gr = row0 + r;
        float4 v = make_float4(0.f, 0.f, 0.f, 0.f);
        if (gr < N) v = *(const float4*)&x[gr * 128 + c];
        *(float4*)&xs[r * 128 + c] = v;
    }
    __syncthreads();
    int j = t & 127;
    int half = t >> 7;             // 0/1 -> rows [half*32, half*32+32)
    float acc[32];
#pragma unroll
    for (int r = 0; r < 32; r++) acc[r] = 0.f;
    for (int k4 = 0; k4 < 128; k4 += 4) {
        float w0 = W1[(k4 + 0) * 128 + j];
        float w1 = W1[(k4 + 1) * 128 + j];
        float w2 = W1[(k4 + 2) * 128 + j];
        float w3 = W1[(k4 + 3) * 128 + j];
#pragma unroll
        for (int r = 0; r < 32; r++) {
            float4 xv = *(const float4*)&xs[(half * 32 + r) * 128 + k4];
            acc[r] += xv.x * w0 + xv.y * w1 + xv.z * w2 + xv.w * w3;
        }
    }
    for (int r = 0; r < 32; r++) {
        int gr = row0 + half * 32 + r;
        if (gr < N) h1[gr * 128 + j] = acc[r];
    }
}

// ---------------- per-node attention coefficients, layer 1 -------------------
__global__ void alpha1_kernel(const float* __restrict__ h1,
                              const float* __restrict__ a_s, const float* __restrict__ a_d,
                              float* __restrict__ as_n, float* __restrict__ ad_n, int N) {
    int gid = blockIdx.x * blockDim.x + threadIdx.x;
    if (gid >= N * 8) return;
    int n = gid >> 3, hd = gid & 7;
    const float* hp = h1 + n * 128 + hd * 16;
    const float* sp = a_s + hd * 16;
    const float* dp = a_d + hd * 16;
    float s = 0.f, d = 0.f;
#pragma unroll
    for (int i = 0; i < 4; i++) {
        float4 hv = *(const float4*)&hp[i * 4];
        float4 sv = *(const float4*)&sp[i * 4];
        float4 dv = *(const float4*)&dp[i * 4];
        s += hv.x * sv.x + hv.y * sv.y + hv.z * sv.z + hv.w * sv.w;
        d += hv.x * dv.x + hv.y * dv.y + hv.z * dv.z + hv.w * dv.w;
    }
    as_n[gid] = s;
    ad_n[gid] = d;
}

// ---------------- edge pass, layer 1 (one wave per edge) ---------------------
__global__ void edge1_kernel(const int* __restrict__ idx, const int* __restrict__ flagp,
                             const float* __restrict__ as_n, const float* __restrict__ ad_n,
                             const float* __restrict__ h1,
                             float* __restrict__ denom1, float* __restrict__ acc1,
                             int E, int N) {
    int wid = (int)((blockIdx.x * (unsigned)blockDim.x + threadIdx.x) >> 6);
    int lane = threadIdx.x & 63;
    if (wid >= E + N) return;
    int src, dst;
    if (wid < E) {
        if (*flagp) { src = idx[wid]; dst = idx[E + wid]; }
        else        { src = idx[2 * wid]; dst = idx[2 * (E + wid)]; }
    } else {
        src = dst = wid - E;
    }
    int c = lane << 1;          // channels [c, c+1], both in head c/16
    int hd = lane >> 3;
    float e = as_n[src * 8 + hd] + ad_n[dst * 8 + hd];
    float w = expf(lrelu(e));
    if (lane < 8) {
        float e2 = as_n[src * 8 + lane] + ad_n[dst * 8 + lane];
        unsafeAtomicAdd(&denom1[dst * 8 + lane], expf(lrelu(e2)));
    }
    float2 hv = *(const float2*)&h1[src * 128 + c];
    unsafeAtomicAdd(&acc1[dst * 128 + c],     hv.x * w);
    unsafeAtomicAdd(&acc1[dst * 128 + c + 1], hv.y * w);
}

// ---------------- finish layer 1: normalize + bias + ELU (in-place to h1) ----
__global__ void finish1_kernel(const float* __restrict__ acc1, const float* __restrict__ denom1,
                               const float* __restrict__ b1, float* __restrict__ h1act, int N) {
    int gid = blockIdx.x * blockDim.x + threadIdx.x;
    if (gid >= N * 128) return;
    int j = gid & 127, n = gid >> 7;
    float v = acc1[gid] / (denom1[n * 8 + (j >> 4)] + 1e-16f) + b1[j];
    h1act[gid] = (v > 0.f) ? v : (expf(v) - 1.f);
}

// ---------------- GEMM2: h2[N,64] = h1act[N,128] @ W2[128,64] ----------------
__global__ __launch_bounds__(256) void gemm2_kernel(
    const float* __restrict__ h1, const float* __restrict__ W2,
    float* __restrict__ h2, int N) {
    __shared__ float xs[64 * 128];
    int row0 = blockIdx.x * 64;
    int t = threadIdx.x;
    for (int i = t; i < 64 * 128 / 4; i += 256) {
        int r = (i * 4) / 128, c = (i * 4) % 128;
        int gr = row0 + r;
        float4 v = make_float4(0.f, 0.f, 0.f, 0.f);
        if (gr < N) v = *(const float4*)&h1[gr * 128 + c];
        *(float4*)&xs[r * 128 + c] = v;
    }
    __syncthreads();
    int j = t & 63;
    int q = t >> 6;               // 0..3 -> rows [q*16, q*16+16)
    float acc[16];
#pragma unroll
    for (int r = 0; r < 16; r++) acc[r] = 0.f;
    for (int k4 = 0; k4 < 128; k4 += 4) {
        float w0 = W2[(k4 + 0) * 64 + j];
        float w1 = W2[(k4 + 1) * 64 + j];
        float w2 = W2[(k4 + 2) * 64 + j];
        float w3 = W2[(k4 + 3) * 64 + j];
#pragma unroll
        for (int r = 0; r < 16; r++) {
            float4 xv = *(const float4*)&xs[(q * 16 + r) * 128 + k4];
            acc[r] += xv.x * w0 + xv.y * w1 + xv.z * w2 + xv.w * w3;
        }
    }
    for (int r = 0; r < 16; r++) {
        int gr = row0 + q * 16 + r;
        if (gr < N) h2[gr * 64 + j] = acc[r];
    }
}

// ---------------- per-node attention coefficients, layer 2 -------------------
__global__ void alpha2_kernel(const float* __restrict__ h2,
                              const float* __restrict__ a_s, const float* __restrict__ a_d,
                              float* __restrict__ as_n, float* __restrict__ ad_n, int N) {
    int node = blockIdx.x * 4 + (threadIdx.x >> 6);
    int lane = threadIdx.x & 63;
    if (node >= N) return;
    float v = h2[node * 64 + lane];
    float s = v * a_s[lane];
    float d = v * a_d[lane];
#pragma unroll
    for (int m = 32; m > 0; m >>= 1) {
        s += __shfl_xor(s, m, 64);
        d += __shfl_xor(d, m, 64);
    }
    if (lane == 0) { as_n[node] = s; ad_n[node] = d; }
}

// ---------------- edge pass, layer 2 (one wave per edge) ---------------------
__global__ void edge2_kernel(const int* __restrict__ idx, const int* __restrict__ flagp,
                             const float* __restrict__ as_n, const float* __restrict__ ad_n,
                             const float* __restrict__ h2,
                             float* __restrict__ denom2, float* __restrict__ acc2,
                             int E, int N) {
    int wid = (int)((blockIdx.x * (unsigned)blockDim.x + threadIdx.x) >> 6);
    int lane = threadIdx.x & 63;
    if (wid >= E + N) return;
    int src, dst;
    if (wid < E) {
        if (*flagp) { src = idx[wid]; dst = idx[E + wid]; }
        else        { src = idx[2 * wid]; dst = idx[2 * (E + wid)]; }
    } else {
        src = dst = wid - E;
    }
    float e = as_n[src] + ad_n[dst];
    float w = expf(lrelu(e));
    if (lane == 0) unsafeAtomicAdd(&denom2[dst], w);
    float hv = h2[src * 64 + lane];
    unsafeAtomicAdd(&acc2[dst * 64 + lane], hv * w);
}

// ---------------- final: normalize + bias + log_softmax ----------------------
__global__ void final_kernel(const float* __restrict__ acc2, const float* __restrict__ denom2,
                             const float* __restrict__ b2, float* __restrict__ out, int N) {
    int node = blockIdx.x * 4 + (threadIdx.x >> 6);
    int lane = threadIdx.x & 63;
    if (node >= N) return;
    float v = acc2[node * 64 + lane] / (denom2[node] + 1e-16f) + b2[lane];
    float m = v;
#pragma unroll
    for (int s = 32; s > 0; s >>= 1) m = fmaxf(m, __shfl_xor(m, s, 64));
    float ex = expf(v - m);
#pragma unroll
    for (int s = 32; s > 0; s >>= 1) ex += __shfl_xor(ex, s, 64);
    out[node * 64 + lane] = v - m - logf(ex);
}

extern "C" void kernel_launch(void* const* d_in, const int* in_sizes, int n_in,
                              void* d_out, int out_size, void* d_ws, size_t ws_size,
                              hipStream_t stream) {
    const float* x   = (const float*)d_in[0];
    const int*   idx = (const int*)d_in[1];
    const float* W1  = (const float*)d_in[2];
    const float* as1 = (const float*)d_in[3];
    const float* ad1 = (const float*)d_in[4];
    const float* b1  = (const float*)d_in[5];
    const float* W2  = (const float*)d_in[6];
    const float* as2 = (const float*)d_in[7];
    const float* ad2 = (const float*)d_in[8];
    const float* b2  = (const float*)d_in[9];
    float* out = (float*)d_out;

    const int N = in_sizes[0] / IN_DIM;
    const int E = in_sizes[1] / 2;

    // workspace layout (floats)
    float* w = (float*)d_ws;
    float* h1     = w;                   // N*128 (reused as h1act in-place)
    float* acc1   = h1 + (size_t)N * 128;  // N*128
    float* denom1 = acc1 + (size_t)N * 128; // N*8  (contiguous with acc1 for one memset)
    float* as1n   = denom1 + (size_t)N * 8; // N*8
    float* ad1n   = as1n + (size_t)N * 8;   // N*8
    float* h2     = ad1n + (size_t)N * 8;   // N*64
    float* acc2   = h2 + (size_t)N * 64;    // N*64
    float* denom2 = acc2 + (size_t)N * 64;  // N (contiguous with acc2)
    float* as2n   = denom2 + (size_t)N;     // N
    float* ad2n   = as2n + (size_t)N;       // N
    int*   flag   = (int*)(ad2n + (size_t)N);
    (void)ws_size; (void)n_in; (void)out_size;

    // zero accumulators + denominators
    hipMemsetAsync(acc1, 0, (size_t)N * 136 * sizeof(float), stream);   // acc1 + denom1
    hipMemsetAsync(acc2, 0, (size_t)N * 65 * sizeof(float), stream);    // acc2 + denom2

    detect_kernel<<<1, 64, 0, stream>>>(idx, flag);

    gemm1_kernel<<<(N + 63) / 64, 256, 0, stream>>>(x, W1, h1, N);
    alpha1_kernel<<<(N * 8 + 255) / 256, 256, 0, stream>>>(h1, as1, ad1, as1n, ad1n, N);

    {
        long long waves = (long long)E + N;
        int blocks = (int)((waves * 64 + 255) / 256);
        edge1_kernel<<<blocks, 256, 0, stream>>>(idx, flag, as1n, ad1n, h1, denom1, acc1, E, N);
    }

    finish1_kernel<<<(N * 128 + 255) / 256, 256, 0, stream>>>(acc1, denom1, b1, h1, N);

    gemm2_kernel<<<(N + 63) / 64, 256, 0, stream>>>(h1, W2, h2, N);
    alpha2_kernel<<<(N + 3) / 4, 256, 0, stream>>>(h2, as2, ad2, as2n, ad2n, N);

    {
        long long waves = (long long)E + N;
        int blocks = (int)((waves * 64 + 255) / 256);
        edge2_kernel<<<blocks, 256, 0, stream>>>(idx, flag, as2n, ad2n, h2, denom2, acc2, E, N);
    }

    final_kernel<<<(N + 3) / 4, 256, 0, stream>>>(acc2, denom2, b2, out, N);
}

// Round 2
// 490.021 us; speedup vs baseline: 2.5061x; 2.5061x over previous
//
#include <hip/hip_runtime.h>
#include <hip/hip_bf16.h>
#include <math.h>

#define IN_DIM 128
#define HID 128
#define HEADS 8
#define OUT_DIM 64
#define SLOPE 0.2f

__device__ __forceinline__ float lrelu(float x) { return fmaxf(x, SLOPE * x); }

// ---------------- dtype detection for edge_index (int32 vs int64 storage) ---
__global__ void detect_kernel(const int* __restrict__ idx, int* __restrict__ flag) {
    if (blockIdx.x == 0 && threadIdx.x == 0) {
        int nz = 0;
        for (int i = 1; i < 1024; i += 2) nz += (idx[i] != 0);
        *flag = (nz > 16) ? 1 : 0;   // 1 => int32 storage, 0 => int64 storage
    }
}

// ---------------- CSR build: histogram of dst --------------------------------
__global__ void hist_kernel(const int* __restrict__ idx, const int* __restrict__ flagp,
                            int* __restrict__ deg, int E, int N) {
    int e = blockIdx.x * blockDim.x + threadIdx.x;
    if (e >= E + N) return;
    int dst;
    if (e < E) dst = (*flagp) ? idx[E + e] : idx[2 * (E + e)];
    else       dst = e - E;
    atomicAdd(&deg[dst], 1);
}

// ---------------- CSR build: exclusive prefix sum (single block) -------------
__global__ __launch_bounds__(1024) void scan_kernel(
    const int* __restrict__ deg, int* __restrict__ row_start,
    int* __restrict__ cursor, int N) {
    __shared__ int wsums[16];
    __shared__ int s_carry;
    int t = threadIdx.x;
    int lane = t & 63, wv = t >> 6;
    if (t == 0) s_carry = 0;
    __syncthreads();
    for (int base = 0; base < N; base += 1024) {
        int i = base + t;
        int v = (i < N) ? deg[i] : 0;
        int incl = v;
#pragma unroll
        for (int off = 1; off < 64; off <<= 1) {
            int u = __shfl_up(incl, off, 64);
            if (lane >= off) incl += u;
        }
        if (lane == 63) wsums[wv] = incl;
        __syncthreads();
        int wave_off = 0;
        for (int k = 0; k < wv; k++) wave_off += wsums[k];
        int carry = s_carry;
        int excl = carry + wave_off + incl - v;
        if (i < N) { row_start[i] = excl; cursor[i] = excl; }
        __syncthreads();
        if (t == 1023) s_carry = carry + wave_off + incl;
        __syncthreads();
    }
    if (t == 0) row_start[N] = s_carry;
}

// ---------------- CSR build: scatter src into dst-sorted order ---------------
__global__ void scatter_kernel(const int* __restrict__ idx, const int* __restrict__ flagp,
                               int* __restrict__ cursor, int* __restrict__ sorted_src,
                               int E, int N) {
    int e = blockIdx.x * blockDim.x + threadIdx.x;
    if (e >= E + N) return;
    int src, dst;
    if (e < E) {
        if (*flagp) { src = idx[e]; dst = idx[E + e]; }
        else        { src = idx[2 * e]; dst = idx[2 * (E + e)]; }
    } else {
        src = dst = e - E;
    }
    int pos = atomicAdd(&cursor[dst], 1);
    sorted_src[pos] = src;
}

// ---------------- GEMM1: h1[N,128] = x[N,128] @ W1[128,128] ------------------
__global__ __launch_bounds__(256) void gemm1_kernel(
    const float* __restrict__ x, const float* __restrict__ W1,
    float* __restrict__ h1, int N) {
    __shared__ float xs[64 * 128];
    int row0 = blockIdx.x * 64;
    int t = threadIdx.x;
    for (int i = t; i < 64 * 128 / 4; i += 256) {
        int r = (i * 4) / 128, c = (i * 4) % 128;
        int gr = row0 + r;
        float4 v = make_float4(0.f, 0.f, 0.f, 0.f);
        if (gr < N) v = *(const float4*)&x[gr * 128 + c];
        *(float4*)&xs[r * 128 + c] = v;
    }
    __syncthreads();
    int j = t & 127;
    int half = t >> 7;
    float acc[32];
#pragma unroll
    for (int r = 0; r < 32; r++) acc[r] = 0.f;
    for (int k4 = 0; k4 < 128; k4 += 4) {
        float w0 = W1[(k4 + 0) * 128 + j];
        float w1 = W1[(k4 + 1) * 128 + j];
        float w2 = W1[(k4 + 2) * 128 + j];
        float w3 = W1[(k4 + 3) * 128 + j];
#pragma unroll
        for (int r = 0; r < 32; r++) {
            float4 xv = *(const float4*)&xs[(half * 32 + r) * 128 + k4];
            acc[r] += xv.x * w0 + xv.y * w1 + xv.z * w2 + xv.w * w3;
        }
    }
    for (int r = 0; r < 32; r++) {
        int gr = row0 + half * 32 + r;
        if (gr < N) h1[gr * 128 + j] = acc[r];
    }
}

// ---------------- per-node attention coefficients, layer 1 -------------------
__global__ void alpha1_kernel(const float* __restrict__ h1,
                              const float* __restrict__ a_s, const float* __restrict__ a_d,
                              float* __restrict__ as_n, float* __restrict__ ad_n, int N) {
    int gid = blockIdx.x * blockDim.x + threadIdx.x;
    if (gid >= N * 8) return;
    int n = gid >> 3, hd = gid & 7;
    const float* hp = h1 + n * 128 + hd * 16;
    const float* sp = a_s + hd * 16;
    const float* dp = a_d + hd * 16;
    float s = 0.f, d = 0.f;
#pragma unroll
    for (int i = 0; i < 4; i++) {
        float4 hv = *(const float4*)&hp[i * 4];
        float4 sv = *(const float4*)&sp[i * 4];
        float4 dv = *(const float4*)&dp[i * 4];
        s += hv.x * sv.x + hv.y * sv.y + hv.z * sv.z + hv.w * sv.w;
        d += hv.x * dv.x + hv.y * dv.y + hv.z * dv.z + hv.w * dv.w;
    }
    as_n[gid] = s;
    ad_n[gid] = d;
}

// ---------------- layer-1 aggregation: one wave per dst node -----------------
// Fuses: softmax-weighted gather-sum + normalize + bias + ELU.
__global__ __launch_bounds__(256) void agg1_kernel(
    const int* __restrict__ row_start, const int* __restrict__ sorted_src,
    const float* __restrict__ as_n, const float* __restrict__ ad_n,
    const float* __restrict__ h1, const float* __restrict__ b1,
    float* __restrict__ h1act, int N) {
    int node = blockIdx.x * 4 + (threadIdx.x >> 6);
    int lane = threadIdx.x & 63;
    if (node >= N) return;
    int hd = lane >> 3;          // head for channels [2*lane, 2*lane+1]
    int c = lane << 1;
    float ad = ad_n[node * 8 + hd];
    int beg = row_start[node], end = row_start[node + 1];
    float ax = 0.f, ay = 0.f, denom = 0.f;
    int i = beg;
    for (; i + 1 < end; i += 2) {
        int s0 = sorted_src[i], s1 = sorted_src[i + 1];
        float w0 = expf(lrelu(as_n[s0 * 8 + hd] + ad));
        float w1 = expf(lrelu(as_n[s1 * 8 + hd] + ad));
        float2 v0 = *(const float2*)&h1[s0 * 128 + c];
        float2 v1 = *(const float2*)&h1[s1 * 128 + c];
        ax += w0 * v0.x + w1 * v1.x;
        ay += w0 * v0.y + w1 * v1.y;
        denom += w0 + w1;
    }
    if (i < end) {
        int s0 = sorted_src[i];
        float w0 = expf(lrelu(as_n[s0 * 8 + hd] + ad));
        float2 v0 = *(const float2*)&h1[s0 * 128 + c];
        ax += w0 * v0.x; ay += w0 * v0.y; denom += w0;
    }
    float inv = 1.f / (denom + 1e-16f);
    float vx = ax * inv + b1[c];
    float vy = ay * inv + b1[c + 1];
    vx = (vx > 0.f) ? vx : (expf(vx) - 1.f);
    vy = (vy > 0.f) ? vy : (expf(vy) - 1.f);
    *(float2*)&h1act[node * 128 + c] = make_float2(vx, vy);
}

// ---------------- GEMM2: h2[N,64] = h1act[N,128] @ W2[128,64] ----------------
__global__ __launch_bounds__(256) void gemm2_kernel(
    const float* __restrict__ h1, const float* __restrict__ W2,
    float* __restrict__ h2, int N) {
    __shared__ float xs[64 * 128];
    int row0 = blockIdx.x * 64;
    int t = threadIdx.x;
    for (int i = t; i < 64 * 128 / 4; i += 256) {
        int r = (i * 4) / 128, c = (i * 4) % 128;
        int gr = row0 + r;
        float4 v = make_float4(0.f, 0.f, 0.f, 0.f);
        if (gr < N) v = *(const float4*)&h1[gr * 128 + c];
        *(float4*)&xs[r * 128 + c] = v;
    }
    __syncthreads();
    int j = t & 63;
    int q = t >> 6;
    float acc[16];
#pragma unroll
    for (int r = 0; r < 16; r++) acc[r] = 0.f;
    for (int k4 = 0; k4 < 128; k4 += 4) {
        float w0 = W2[(k4 + 0) * 64 + j];
        float w1 = W2[(k4 + 1) * 64 + j];
        float w2 = W2[(k4 + 2) * 64 + j];
        float w3 = W2[(k4 + 3) * 64 + j];
#pragma unroll
        for (int r = 0; r < 16; r++) {
            float4 xv = *(const float4*)&xs[(q * 16 + r) * 128 + k4];
            acc[r] += xv.x * w0 + xv.y * w1 + xv.z * w2 + xv.w * w3;
        }
    }
    for (int r = 0; r < 16; r++) {
        int gr = row0 + q * 16 + r;
        if (gr < N) h2[gr * 64 + j] = acc[r];
    }
}

// ---------------- per-node attention coefficients, layer 2 -------------------
__global__ void alpha2_kernel(const float* __restrict__ h2,
                              const float* __restrict__ a_s, const float* __restrict__ a_d,
                              float* __restrict__ as_n, float* __restrict__ ad_n, int N) {
    int node = blockIdx.x * 4 + (threadIdx.x >> 6);
    int lane = threadIdx.x & 63;
    if (node >= N) return;
    float v = h2[node * 64 + lane];
    float s = v * a_s[lane];
    float d = v * a_d[lane];
#pragma unroll
    for (int m = 32; m > 0; m >>= 1) {
        s += __shfl_xor(s, m, 64);
        d += __shfl_xor(d, m, 64);
    }
    if (lane == 0) { as_n[node] = s; ad_n[node] = d; }
}

// ---------------- layer-2 aggregation: one wave per dst node -----------------
// Fuses: softmax-weighted gather-sum + normalize + bias + log_softmax.
__global__ __launch_bounds__(256) void agg2_kernel(
    const int* __restrict__ row_start, const int* __restrict__ sorted_src,
    const float* __restrict__ as_n, const float* __restrict__ ad_n,
    const float* __restrict__ h2, const float* __restrict__ b2,
    float* __restrict__ out, int N) {
    int node = blockIdx.x * 4 + (threadIdx.x >> 6);
    int lane = threadIdx.x & 63;
    if (node >= N) return;
    float adv = ad_n[node];
    int beg = row_start[node], end = row_start[node + 1];
    float acc = 0.f, denom = 0.f;
    int i = beg;
    for (; i + 1 < end; i += 2) {
        int s0 = sorted_src[i], s1 = sorted_src[i + 1];
        float w0 = expf(lrelu(as_n[s0] + adv));
        float w1 = expf(lrelu(as_n[s1] + adv));
        acc += w0 * h2[s0 * 64 + lane] + w1 * h2[s1 * 64 + lane];
        denom += w0 + w1;
    }
    if (i < end) {
        int s0 = sorted_src[i];
        float w0 = expf(lrelu(as_n[s0] + adv));
        acc += w0 * h2[s0 * 64 + lane];
        denom += w0;
    }
    float v = acc / (denom + 1e-16f) + b2[lane];
    float m = v;
#pragma unroll
    for (int s = 32; s > 0; s >>= 1) m = fmaxf(m, __shfl_xor(m, s, 64));
    float ex = expf(v - m);
#pragma unroll
    for (int s = 32; s > 0; s >>= 1) ex += __shfl_xor(ex, s, 64);
    out[node * 64 + lane] = v - m - logf(ex);
}

extern "C" void kernel_launch(void* const* d_in, const int* in_sizes, int n_in,
                              void* d_out, int out_size, void* d_ws, size_t ws_size,
                              hipStream_t stream) {
    const float* x   = (const float*)d_in[0];
    const int*   idx = (const int*)d_in[1];
    const float* W1  = (const float*)d_in[2];
    const float* as1 = (const float*)d_in[3];
    const float* ad1 = (const float*)d_in[4];
    const float* b1  = (const float*)d_in[5];
    const float* W2  = (const float*)d_in[6];
    const float* as2 = (const float*)d_in[7];
    const float* ad2 = (const float*)d_in[8];
    const float* b2  = (const float*)d_in[9];
    float* out = (float*)d_out;

    const int N = in_sizes[0] / IN_DIM;
    const int E = in_sizes[1] / 2;
    const int EN = E + N;

    // workspace layout
    float* w = (float*)d_ws;
    float* h1     = w;                        // N*128
    float* h1act  = h1 + (size_t)N * 128;     // N*128
    float* h2     = h1act + (size_t)N * 128;  // N*64
    float* as1n   = h2 + (size_t)N * 64;      // N*8
    float* ad1n   = as1n + (size_t)N * 8;     // N*8
    float* as2n   = ad1n + (size_t)N * 8;     // N
    float* ad2n   = as2n + (size_t)N;         // N
    int* deg       = (int*)(ad2n + (size_t)N); // N
    int* row_start = deg + N;                  // N+1
    int* cursor    = row_start + N + 1;        // N
    int* sorted_src= cursor + N;               // E+N
    int* flag      = sorted_src + EN;          // 1
    (void)ws_size; (void)n_in; (void)out_size;

    hipMemsetAsync(deg, 0, (size_t)N * sizeof(int), stream);

    detect_kernel<<<1, 64, 0, stream>>>(idx, flag);
    hist_kernel<<<(EN + 255) / 256, 256, 0, stream>>>(idx, flag, deg, E, N);
    scan_kernel<<<1, 1024, 0, stream>>>(deg, row_start, cursor, N);
    scatter_kernel<<<(EN + 255) / 256, 256, 0, stream>>>(idx, flag, cursor, sorted_src, E, N);

    gemm1_kernel<<<(N + 63) / 64, 256, 0, stream>>>(x, W1, h1, N);
    alpha1_kernel<<<(N * 8 + 255) / 256, 256, 0, stream>>>(h1, as1, ad1, as1n, ad1n, N);
    agg1_kernel<<<(N + 3) / 4, 256, 0, stream>>>(row_start, sorted_src, as1n, ad1n, h1, b1, h1act, N);

    gemm2_kernel<<<(N + 63) / 64, 256, 0, stream>>>(h1act, W2, h2, N);
    alpha2_kernel<<<(N + 3) / 4, 256, 0, stream>>>(h2, as2, ad2, as2n, ad2n, N);
    agg2_kernel<<<(N + 3) / 4, 256, 0, stream>>>(row_start, sorted_src, as2n, ad2n, h2, b2, out, N);
}

// Round 3
// 371.656 us; speedup vs baseline: 3.3043x; 1.3185x over previous
//
#include <hip/hip_runtime.h>
#include <hip/hip_bf16.h>
#include <math.h>

#define IN_DIM 128
#define HID 128
#define HEADS 8
#define OUT_DIM 64
#define SLOPE 0.2f

__device__ __forceinline__ float lrelu(float x) { return fmaxf(x, SLOPE * x); }
__device__ __forceinline__ float bf2f(unsigned u) { return __uint_as_float(u << 16); }
__device__ __forceinline__ unsigned short f2bf(float f) {
    unsigned u = __float_as_uint(f);
    return (unsigned short)((u + 0x7FFF + ((u >> 16) & 1)) >> 16);  // RNE
}

// ---------------- dtype detection for edge_index (int32 vs int64 storage) ---
__global__ void detect_kernel(const int* __restrict__ idx, int* __restrict__ flag) {
    int lane = threadIdx.x;  // 64 threads
    int nz = 0;
    for (int i = 2 * lane + 1; i < 1024; i += 128) nz += (idx[i] != 0);
#pragma unroll
    for (int m = 32; m > 0; m >>= 1) nz += __shfl_xor(nz, m, 64);
    if (lane == 0) *flag = (nz > 16) ? 1 : 0;  // 1 => int32, 0 => int64
}

// ---------------- CSR build: histogram of dst --------------------------------
__global__ void hist_kernel(const int* __restrict__ idx, const int* __restrict__ flagp,
                            int* __restrict__ deg, int E, int N) {
    int e = blockIdx.x * blockDim.x + threadIdx.x;
    if (e >= E + N) return;
    int dst;
    if (e < E) dst = (*flagp) ? idx[E + e] : idx[2 * (E + e)];
    else       dst = e - E;
    atomicAdd(&deg[dst], 1);
}

// ---------------- CSR build: multi-block exclusive scan ----------------------
// Phase A: per-block (1024-elem tile) local exclusive scan + block totals.
__global__ __launch_bounds__(256) void scanA_kernel(
    const int* __restrict__ deg, int* __restrict__ row_start,
    int* __restrict__ bsum, int N) {
    __shared__ int wtot[4];
    int b = blockIdx.x, t = threadIdx.x;
    int base = b * 1024 + t * 4;
    int4 v = make_int4(0, 0, 0, 0);
    if (base + 3 < N) v = *(const int4*)&deg[base];
    else {
        if (base < N) v.x = deg[base];
        if (base + 1 < N) v.y = deg[base + 1];
        if (base + 2 < N) v.z = deg[base + 2];
        if (base + 3 < N) v.w = deg[base + 3];
    }
    int tsum = v.x + v.y + v.z + v.w;
    int lane = t & 63, wv = t >> 6;
    int incl = tsum;
#pragma unroll
    for (int off = 1; off < 64; off <<= 1) {
        int u = __shfl_up(incl, off, 64);
        if (lane >= off) incl += u;
    }
    if (lane == 63) wtot[wv] = incl;
    __syncthreads();
    int woff = 0;
    for (int k = 0; k < wv; k++) woff += wtot[k];
    int e0 = woff + incl - tsum;
    int e1 = e0 + v.x, e2 = e1 + v.y, e3 = e2 + v.z;
    if (base < N) row_start[base] = e0;
    if (base + 1 < N) row_start[base + 1] = e1;
    if (base + 2 < N) row_start[base + 2] = e2;
    if (base + 3 < N) row_start[base + 3] = e3;
    if (t == 255) bsum[b] = woff + incl;   // block total
}

// Phase B: single-wave scan of block totals (exclusive, in place).
__global__ void scanB_kernel(int* __restrict__ bsum, int nb) {
    int lane = threadIdx.x;  // 64
    int carry = 0;
    for (int base = 0; base < nb; base += 64) {
        int i = base + lane;
        int v = (i < nb) ? bsum[i] : 0;
        int incl = v;
#pragma unroll
        for (int off = 1; off < 64; off <<= 1) {
            int u = __shfl_up(incl, off, 64);
            if (lane >= off) incl += u;
        }
        if (i < nb) bsum[i] = carry + incl - v;
        carry += __shfl(incl, 63, 64);
    }
}

// Phase C: add block offsets, emit cursor copy and row_start[N].
__global__ __launch_bounds__(256) void scanC_kernel(
    int* __restrict__ row_start, int* __restrict__ cursor,
    const int* __restrict__ bsum, int N, int total) {
    int b = blockIdx.x, t = threadIdx.x;
    int off = bsum[b];
    int base = b * 1024 + t * 4;
#pragma unroll
    for (int k = 0; k < 4; k++) {
        int i = base + k;
        if (i < N) {
            int val = row_start[i] + off;
            row_start[i] = val;
            cursor[i] = val;
        }
    }
    if (b == 0 && t == 0) row_start[N] = total;
}

// ---------------- CSR build: scatter src into dst-sorted order ---------------
__global__ void scatter_kernel(const int* __restrict__ idx, const int* __restrict__ flagp,
                               int* __restrict__ cursor, int* __restrict__ sorted_src,
                               int E, int N) {
    int e = blockIdx.x * blockDim.x + threadIdx.x;
    if (e >= E + N) return;
    int src, dst;
    if (e < E) {
        if (*flagp) { src = idx[e]; dst = idx[E + e]; }
        else        { src = idx[2 * e]; dst = idx[2 * (E + e)]; }
    } else {
        src = dst = e - E;
    }
    int pos = atomicAdd(&cursor[dst], 1);
    sorted_src[pos] = src;
}

// ---------------- GEMM1: h1g[N,128](bf16) = x[N,128] @ W1[128,128] -----------
__global__ __launch_bounds__(256) void gemm1_kernel(
    const float* __restrict__ x, const float* __restrict__ W1,
    unsigned short* __restrict__ h1g, int N) {
    __shared__ float xs[64 * 128];
    int row0 = blockIdx.x * 64;
    int t = threadIdx.x;
    for (int i = t; i < 64 * 128 / 4; i += 256) {
        int r = (i * 4) / 128, c = (i * 4) % 128;
        int gr = row0 + r;
        float4 v = make_float4(0.f, 0.f, 0.f, 0.f);
        if (gr < N) v = *(const float4*)&x[gr * 128 + c];
        *(float4*)&xs[r * 128 + c] = v;
    }
    __syncthreads();
    int j = t & 127;
    int half = t >> 7;
    float acc[32];
#pragma unroll
    for (int r = 0; r < 32; r++) acc[r] = 0.f;
    for (int k4 = 0; k4 < 128; k4 += 4) {
        float w0 = W1[(k4 + 0) * 128 + j];
        float w1 = W1[(k4 + 1) * 128 + j];
        float w2 = W1[(k4 + 2) * 128 + j];
        float w3 = W1[(k4 + 3) * 128 + j];
#pragma unroll
        for (int r = 0; r < 32; r++) {
            float4 xv = *(const float4*)&xs[(half * 32 + r) * 128 + k4];
            acc[r] += xv.x * w0 + xv.y * w1 + xv.z * w2 + xv.w * w3;
        }
    }
    for (int r = 0; r < 32; r++) {
        int gr = row0 + half * 32 + r;
        if (gr < N) h1g[(size_t)gr * 128 + j] = f2bf(acc[r]);
    }
}

// ---------------- per-node attention coefficients, layer 1 (bf16 h) ----------
__global__ void alpha1_kernel(const unsigned short* __restrict__ h1g,
                              const float* __restrict__ a_s, const float* __restrict__ a_d,
                              float* __restrict__ as_n, float* __restrict__ ad_n, int N) {
    int gid = blockIdx.x * blockDim.x + threadIdx.x;
    if (gid >= N * 8) return;
    int n = gid >> 3, hd = gid & 7;
    const uint4* hp = (const uint4*)(h1g + (size_t)n * 128 + hd * 16);
    uint4 u0 = hp[0], u1 = hp[1];
    unsigned uu[8] = {u0.x, u0.y, u0.z, u0.w, u1.x, u1.y, u1.z, u1.w};
    const float* sp = a_s + hd * 16;
    const float* dp = a_d + hd * 16;
    float s = 0.f, d = 0.f;
#pragma unroll
    for (int k = 0; k < 8; k++) {
        float lo = bf2f(uu[k] & 0xffffu), hi = bf2f(uu[k] >> 16);
        s += lo * sp[2 * k] + hi * sp[2 * k + 1];
        d += lo * dp[2 * k] + hi * dp[2 * k + 1];
    }
    as_n[gid] = s;
    ad_n[gid] = d;
}

// ---------------- layer-1 aggregation: one wave per dst node -----------------
// 4-edge unroll; lanes 0-31 compute the 4x8 (edge,head) weights, shfl-broadcast.
__global__ __launch_bounds__(256) void agg1_kernel(
    const int* __restrict__ row_start, const int* __restrict__ sorted_src,
    const float* __restrict__ as_n, const float* __restrict__ ad_n,
    const unsigned short* __restrict__ h1g, const float* __restrict__ b1,
    float* __restrict__ h1act, int N) {
    int node = blockIdx.x * 4 + (threadIdx.x >> 6);
    int lane = threadIdx.x & 63;
    if (node >= N) return;
    int hd = lane >> 3;           // my head (channels 2*lane, 2*lane+1)
    int c = lane << 1;
    float ad8 = ad_n[node * 8 + (lane & 7)];   // for weight-computation role
    float adv = ad_n[node * 8 + hd];           // for cleanup loop
    int beg = row_start[node], end = row_start[node + 1];
    float ax = 0.f, ay = 0.f, denom = 0.f;
    int i = beg;
    for (; i + 3 < end; i += 4) {
        int s0 = sorted_src[i], s1 = sorted_src[i + 1];
        int s2 = sorted_src[i + 2], s3 = sorted_src[i + 3];
        int jj = (lane >> 3) & 3;
        int sj = (jj == 0) ? s0 : (jj == 1) ? s1 : (jj == 2) ? s2 : s3;
        float wall = expf(lrelu(as_n[sj * 8 + (lane & 7)] + ad8));
        float w0 = __shfl(wall, hd, 64);
        float w1 = __shfl(wall, 8 + hd, 64);
        float w2 = __shfl(wall, 16 + hd, 64);
        float w3 = __shfl(wall, 24 + hd, 64);
        unsigned v0 = *(const unsigned*)&h1g[(size_t)s0 * 128 + c];
        unsigned v1 = *(const unsigned*)&h1g[(size_t)s1 * 128 + c];
        unsigned v2 = *(const unsigned*)&h1g[(size_t)s2 * 128 + c];
        unsigned v3 = *(const unsigned*)&h1g[(size_t)s3 * 128 + c];
        ax += w0 * bf2f(v0 & 0xffffu) + w1 * bf2f(v1 & 0xffffu)
            + w2 * bf2f(v2 & 0xffffu) + w3 * bf2f(v3 & 0xffffu);
        ay += w0 * bf2f(v0 >> 16) + w1 * bf2f(v1 >> 16)
            + w2 * bf2f(v2 >> 16) + w3 * bf2f(v3 >> 16);
        denom += w0 + w1 + w2 + w3;
    }
    for (; i < end; i++) {
        int s0 = sorted_src[i];
        float w0 = expf(lrelu(as_n[s0 * 8 + hd] + adv));
        unsigned v0 = *(const unsigned*)&h1g[(size_t)s0 * 128 + c];
        ax += w0 * bf2f(v0 & 0xffffu);
        ay += w0 * bf2f(v0 >> 16);
        denom += w0;
    }
    float inv = 1.f / (denom + 1e-16f);
    float vx = ax * inv + b1[c];
    float vy = ay * inv + b1[c + 1];
    vx = (vx > 0.f) ? vx : (expf(vx) - 1.f);
    vy = (vy > 0.f) ? vy : (expf(vy) - 1.f);
    *(float2*)&h1act[(size_t)node * 128 + c] = make_float2(vx, vy);
}

// ---------------- GEMM2: h2g[N,64](bf16) = h1act[N,128] @ W2[128,64] ---------
__global__ __launch_bounds__(256) void gemm2_kernel(
    const float* __restrict__ h1, const float* __restrict__ W2,
    unsigned short* __restrict__ h2g, int N) {
    __shared__ float xs[64 * 128];
    int row0 = blockIdx.x * 64;
    int t = threadIdx.x;
    for (int i = t; i < 64 * 128 / 4; i += 256) {
        int r = (i * 4) / 128, c = (i * 4) % 128;
        int gr = row0 + r;
        float4 v = make_float4(0.f, 0.f, 0.f, 0.f);
        if (gr < N) v = *(const float4*)&h1[(size_t)gr * 128 + c];
        *(float4*)&xs[r * 128 + c] = v;
    }
    __syncthreads();
    int j = t & 63;
    int q = t >> 6;
    float acc[16];
#pragma unroll
    for (int r = 0; r < 16; r++) acc[r] = 0.f;
    for (int k4 = 0; k4 < 128; k4 += 4) {
        float w0 = W2[(k4 + 0) * 64 + j];
        float w1 = W2[(k4 + 1) * 64 + j];
        float w2 = W2[(k4 + 2) * 64 + j];
        float w3 = W2[(k4 + 3) * 64 + j];
#pragma unroll
        for (int r = 0; r < 16; r++) {
            float4 xv = *(const float4*)&xs[(q * 16 + r) * 128 + k4];
            acc[r] += xv.x * w0 + xv.y * w1 + xv.z * w2 + xv.w * w3;
        }
    }
    for (int r = 0; r < 16; r++) {
        int gr = row0 + q * 16 + r;
        if (gr < N) h2g[(size_t)gr * 64 + j] = f2bf(acc[r]);
    }
}

// ---------------- per-node attention coefficients, layer 2 -------------------
__global__ void alpha2_kernel(const unsigned short* __restrict__ h2g,
                              const float* __restrict__ a_s, const float* __restrict__ a_d,
                              float* __restrict__ as_n, float* __restrict__ ad_n, int N) {
    int node = blockIdx.x * 4 + (threadIdx.x >> 6);
    int lane = threadIdx.x & 63;
    if (node >= N) return;
    float v = bf2f(h2g[(size_t)node * 64 + lane]);
    float s = v * a_s[lane];
    float d = v * a_d[lane];
#pragma unroll
    for (int m = 32; m > 0; m >>= 1) {
        s += __shfl_xor(s, m, 64);
        d += __shfl_xor(d, m, 64);
    }
    if (lane == 0) { as_n[node] = s; ad_n[node] = d; }
}

// ---------------- layer-2 aggregation: one wave per dst node -----------------
__global__ __launch_bounds__(256) void agg2_kernel(
    const int* __restrict__ row_start, const int* __restrict__ sorted_src,
    const float* __restrict__ as_n, const float* __restrict__ ad_n,
    const unsigned short* __restrict__ h2g, const float* __restrict__ b2,
    float* __restrict__ out, int N) {
    int node = blockIdx.x * 4 + (threadIdx.x >> 6);
    int lane = threadIdx.x & 63;
    if (node >= N) return;
    float adv = ad_n[node];
    int beg = row_start[node], end = row_start[node + 1];
    float acc = 0.f, denom = 0.f;
    int i = beg;
    for (; i + 3 < end; i += 4) {
        int s0 = sorted_src[i], s1 = sorted_src[i + 1];
        int s2 = sorted_src[i + 2], s3 = sorted_src[i + 3];
        int jj = lane & 3;
        int sj = (jj == 0) ? s0 : (jj == 1) ? s1 : (jj == 2) ? s2 : s3;
        float wall = expf(lrelu(as_n[sj] + adv));
        float w0 = __shfl(wall, 0, 64);
        float w1 = __shfl(wall, 1, 64);
        float w2 = __shfl(wall, 2, 64);
        float w3 = __shfl(wall, 3, 64);
        acc += w0 * bf2f(h2g[(size_t)s0 * 64 + lane])
             + w1 * bf2f(h2g[(size_t)s1 * 64 + lane])
             + w2 * bf2f(h2g[(size_t)s2 * 64 + lane])
             + w3 * bf2f(h2g[(size_t)s3 * 64 + lane]);
        denom += w0 + w1 + w2 + w3;
    }
    for (; i < end; i++) {
        int s0 = sorted_src[i];
        float w0 = expf(lrelu(as_n[s0] + adv));
        acc += w0 * bf2f(h2g[(size_t)s0 * 64 + lane]);
        denom += w0;
    }
    float v = acc / (denom + 1e-16f) + b2[lane];
    float m = v;
#pragma unroll
    for (int s = 32; s > 0; s >>= 1) m = fmaxf(m, __shfl_xor(m, s, 64));
    float ex = expf(v - m);
#pragma unroll
    for (int s = 32; s > 0; s >>= 1) ex += __shfl_xor(ex, s, 64);
    out[(size_t)node * 64 + lane] = v - m - logf(ex);
}

extern "C" void kernel_launch(void* const* d_in, const int* in_sizes, int n_in,
                              void* d_out, int out_size, void* d_ws, size_t ws_size,
                              hipStream_t stream) {
    const float* x   = (const float*)d_in[0];
    const int*   idx = (const int*)d_in[1];
    const float* W1  = (const float*)d_in[2];
    const float* as1 = (const float*)d_in[3];
    const float* ad1 = (const float*)d_in[4];
    const float* b1  = (const float*)d_in[5];
    const float* W2  = (const float*)d_in[6];
    const float* as2 = (const float*)d_in[7];
    const float* ad2 = (const float*)d_in[8];
    const float* b2  = (const float*)d_in[9];
    float* out = (float*)d_out;

    const int N = in_sizes[0] / IN_DIM;
    const int E = in_sizes[1] / 2;
    const int EN = E + N;
    const int nb = (N + 1023) / 1024;   // scan tiles

    // workspace layout
    float* fw = (float*)d_ws;
    float* h1act = fw;                         // N*128 f32
    float* as1n  = h1act + (size_t)N * 128;    // N*8
    float* ad1n  = as1n + (size_t)N * 8;       // N*8
    float* as2n  = ad1n + (size_t)N * 8;       // N
    float* ad2n  = as2n + (size_t)N;           // N
    unsigned short* h1g = (unsigned short*)(ad2n + (size_t)N);  // N*128 bf16 (16B-aligned: N*138*4 % 16 == 0 for N=50000)
    unsigned short* h2g = h1g + (size_t)N * 128;                // N*64 bf16
    int* deg        = (int*)(h2g + (size_t)N * 64);
    int* row_start  = deg + N;          // N+1
    int* cursor     = row_start + N + 1;
    int* bsum       = cursor + N;       // nb (<=1024)
    int* sorted_src = bsum + 1024;      // E+N
    int* flag       = sorted_src + EN;
    (void)ws_size; (void)n_in; (void)out_size;

    hipMemsetAsync(deg, 0, (size_t)N * sizeof(int), stream);

    detect_kernel<<<1, 64, 0, stream>>>(idx, flag);
    hist_kernel<<<(EN + 255) / 256, 256, 0, stream>>>(idx, flag, deg, E, N);
    scanA_kernel<<<nb, 256, 0, stream>>>(deg, row_start, bsum, N);
    scanB_kernel<<<1, 64, 0, stream>>>(bsum, nb);
    scanC_kernel<<<nb, 256, 0, stream>>>(row_start, cursor, bsum, N, EN);
    scatter_kernel<<<(EN + 255) / 256, 256, 0, stream>>>(idx, flag, cursor, sorted_src, E, N);

    gemm1_kernel<<<(N + 63) / 64, 256, 0, stream>>>(x, W1, h1g, N);
    alpha1_kernel<<<(N * 8 + 255) / 256, 256, 0, stream>>>(h1g, as1, ad1, as1n, ad1n, N);
    agg1_kernel<<<(N + 3) / 4, 256, 0, stream>>>(row_start, sorted_src, as1n, ad1n, h1g, b1, h1act, N);

    gemm2_kernel<<<(N + 63) / 64, 256, 0, stream>>>(h1act, W2, h2g, N);
    alpha2_kernel<<<(N + 3) / 4, 256, 0, stream>>>(h2g, as2, ad2, as2n, ad2n, N);
    agg2_kernel<<<(N + 3) / 4, 256, 0, stream>>>(row_start, sorted_src, as2n, ad2n, h2g, b2, out, N);
}

// Round 4
// 316.815 us; speedup vs baseline: 3.8763x; 1.1731x over previous
//
#include <hip/hip_runtime.h>
#include <hip/hip_bf16.h>
#include <math.h>

#define IN_DIM 128
#define HID 128
#define HEADS 8
#define OUT_DIM 64
#define SLOPE 0.2f

typedef short bf16x8 __attribute__((ext_vector_type(8)));
typedef float f32x4 __attribute__((ext_vector_type(4)));

__device__ __forceinline__ float lrelu(float x) { return fmaxf(x, SLOPE * x); }
__device__ __forceinline__ float bf2f(unsigned u) { return __uint_as_float(u << 16); }
__device__ __forceinline__ unsigned short f2bf(float f) {
    unsigned u = __float_as_uint(f);
    return (unsigned short)((u + 0x7FFF + ((u >> 16) & 1)) >> 16);  // RNE
}

// ---------------- dtype detection for edge_index (int32 vs int64 storage) ---
__global__ void detect_kernel(const int* __restrict__ idx, int* __restrict__ flag) {
    int lane = threadIdx.x;  // 64 threads
    int nz = 0;
    for (int i = 2 * lane + 1; i < 1024; i += 128) nz += (idx[i] != 0);
#pragma unroll
    for (int m = 32; m > 0; m >>= 1) nz += __shfl_xor(nz, m, 64);
    if (lane == 0) *flag = (nz > 16) ? 1 : 0;  // 1 => int32, 0 => int64
}

// ---------------- CSR build: histogram of dst --------------------------------
__global__ void hist_kernel(const int* __restrict__ idx, const int* __restrict__ flagp,
                            int* __restrict__ deg, int E, int N) {
    int e = blockIdx.x * blockDim.x + threadIdx.x;
    if (e >= E + N) return;
    int dst;
    if (e < E) dst = (*flagp) ? idx[E + e] : idx[2 * (E + e)];
    else       dst = e - E;
    atomicAdd(&deg[dst], 1);
}

// ---------------- CSR build: multi-block exclusive scan ----------------------
__global__ __launch_bounds__(256) void scanA_kernel(
    const int* __restrict__ deg, int* __restrict__ row_start,
    int* __restrict__ bsum, int N) {
    __shared__ int wtot[4];
    int b = blockIdx.x, t = threadIdx.x;
    int base = b * 1024 + t * 4;
    int4 v = make_int4(0, 0, 0, 0);
    if (base + 3 < N) v = *(const int4*)&deg[base];
    else {
        if (base < N) v.x = deg[base];
        if (base + 1 < N) v.y = deg[base + 1];
        if (base + 2 < N) v.z = deg[base + 2];
        if (base + 3 < N) v.w = deg[base + 3];
    }
    int tsum = v.x + v.y + v.z + v.w;
    int lane = t & 63, wv = t >> 6;
    int incl = tsum;
#pragma unroll
    for (int off = 1; off < 64; off <<= 1) {
        int u = __shfl_up(incl, off, 64);
        if (lane >= off) incl += u;
    }
    if (lane == 63) wtot[wv] = incl;
    __syncthreads();
    int woff = 0;
    for (int k = 0; k < wv; k++) woff += wtot[k];
    int e0 = woff + incl - tsum;
    int e1 = e0 + v.x, e2 = e1 + v.y, e3 = e2 + v.z;
    if (base < N) row_start[base] = e0;
    if (base + 1 < N) row_start[base + 1] = e1;
    if (base + 2 < N) row_start[base + 2] = e2;
    if (base + 3 < N) row_start[base + 3] = e3;
    if (t == 255) bsum[b] = woff + incl;
}

__global__ void scanB_kernel(int* __restrict__ bsum, int nb) {
    int lane = threadIdx.x;  // 64
    int carry = 0;
    for (int base = 0; base < nb; base += 64) {
        int i = base + lane;
        int v = (i < nb) ? bsum[i] : 0;
        int incl = v;
#pragma unroll
        for (int off = 1; off < 64; off <<= 1) {
            int u = __shfl_up(incl, off, 64);
            if (lane >= off) incl += u;
        }
        if (i < nb) bsum[i] = carry + incl - v;
        carry += __shfl(incl, 63, 64);
    }
}

__global__ __launch_bounds__(256) void scanC_kernel(
    int* __restrict__ row_start, int* __restrict__ cursor,
    const int* __restrict__ bsum, int N, int total) {
    int b = blockIdx.x, t = threadIdx.x;
    int off = bsum[b];
    int base = b * 1024 + t * 4;
#pragma unroll
    for (int k = 0; k < 4; k++) {
        int i = base + k;
        if (i < N) {
            int val = row_start[i] + off;
            row_start[i] = val;
            cursor[i] = val;
        }
    }
    if (b == 0 && t == 0) row_start[N] = total;
}

// ---------------- CSR build: scatter src into dst-sorted order ---------------
__global__ void scatter_kernel(const int* __restrict__ idx, const int* __restrict__ flagp,
                               int* __restrict__ cursor, int* __restrict__ sorted_src,
                               int E, int N) {
    int e = blockIdx.x * blockDim.x + threadIdx.x;
    if (e >= E + N) return;
    int src, dst;
    if (e < E) {
        if (*flagp) { src = idx[e]; dst = idx[E + e]; }
        else        { src = idx[2 * e]; dst = idx[2 * (E + e)]; }
    } else {
        src = dst = e - E;
    }
    int pos = atomicAdd(&cursor[dst], 1);
    sorted_src[pos] = src;
}

// ---------------- GEMM1 (MFMA): h1g[N,128](bf16) = x[N,128] @ W1[128,128] ----
// Wave tile: 16 rows x 128 cols (8 col-tiles of 16). Block: 4 waves = 64 rows.
__global__ __launch_bounds__(256) void gemm1_kernel(
    const float* __restrict__ x, const float* __restrict__ W1,
    unsigned short* __restrict__ h1g, int N) {
    __shared__ short Wt[128 * 136];   // Wt[n][k] bf16, rows padded to 136
    int t = threadIdx.x;
    for (int id = t; id < 128 * 32; id += 256) {       // 4096 float4 loads
        int k = id >> 5;
        int n0 = (id & 31) * 4;
        float4 v = *(const float4*)&W1[k * 128 + n0];
        Wt[(n0 + 0) * 136 + k] = (short)f2bf(v.x);
        Wt[(n0 + 1) * 136 + k] = (short)f2bf(v.y);
        Wt[(n0 + 2) * 136 + k] = (short)f2bf(v.z);
        Wt[(n0 + 3) * 136 + k] = (short)f2bf(v.w);
    }
    __syncthreads();
    int wv = t >> 6, lane = t & 63;
    int m = lane & 15, q = lane >> 4;
    int row = blockIdx.x * 64 + wv * 16 + m;
    f32x4 acc[8];
#pragma unroll
    for (int j = 0; j < 8; j++) acc[j] = (f32x4){0.f, 0.f, 0.f, 0.f};
#pragma unroll
    for (int k0 = 0; k0 < 128; k0 += 32) {
        bf16x8 a = {0, 0, 0, 0, 0, 0, 0, 0};
        if (row < N) {
            const float* xp = &x[(size_t)row * 128 + k0 + q * 8];
            float4 u0 = *(const float4*)xp;
            float4 u1 = *(const float4*)(xp + 4);
            a[0] = (short)f2bf(u0.x); a[1] = (short)f2bf(u0.y);
            a[2] = (short)f2bf(u0.z); a[3] = (short)f2bf(u0.w);
            a[4] = (short)f2bf(u1.x); a[5] = (short)f2bf(u1.y);
            a[6] = (short)f2bf(u1.z); a[7] = (short)f2bf(u1.w);
        }
#pragma unroll
        for (int j = 0; j < 8; j++) {
            bf16x8 b = *(const bf16x8*)&Wt[(j * 16 + m) * 136 + k0 + q * 8];
            acc[j] = __builtin_amdgcn_mfma_f32_16x16x32_bf16(a, b, acc[j], 0, 0, 0);
        }
    }
    int rbase = blockIdx.x * 64 + wv * 16 + q * 4;
#pragma unroll
    for (int r = 0; r < 4; r++) {
        int rr = rbase + r;
        if (rr < N) {
#pragma unroll
            for (int j = 0; j < 8; j++)
                h1g[(size_t)rr * 128 + j * 16 + m] = f2bf(acc[j][r]);
        }
    }
}

// ---------------- per-node attention coefficients, layer 1 (bf16 h) ----------
__global__ void alpha1_kernel(const unsigned short* __restrict__ h1g,
                              const float* __restrict__ a_s, const float* __restrict__ a_d,
                              float* __restrict__ as_n, float* __restrict__ ad_n, int N) {
    int gid = blockIdx.x * blockDim.x + threadIdx.x;
    if (gid >= N * 8) return;
    int n = gid >> 3, hd = gid & 7;
    const uint4* hp = (const uint4*)(h1g + (size_t)n * 128 + hd * 16);
    uint4 u0 = hp[0], u1 = hp[1];
    unsigned uu[8] = {u0.x, u0.y, u0.z, u0.w, u1.x, u1.y, u1.z, u1.w};
    const float* sp = a_s + hd * 16;
    const float* dp = a_d + hd * 16;
    float s = 0.f, d = 0.f;
#pragma unroll
    for (int k = 0; k < 8; k++) {
        float lo = bf2f(uu[k] & 0xffffu), hi = bf2f(uu[k] >> 16);
        s += lo * sp[2 * k] + hi * sp[2 * k + 1];
        d += lo * dp[2 * k] + hi * dp[2 * k + 1];
    }
    as_n[gid] = s;
    ad_n[gid] = d;
}

// ---------------- layer-1 aggregation: one wave per dst node -----------------
__global__ __launch_bounds__(256) void agg1_kernel(
    const int* __restrict__ row_start, const int* __restrict__ sorted_src,
    const float* __restrict__ as_n, const float* __restrict__ ad_n,
    const unsigned short* __restrict__ h1g, const float* __restrict__ b1,
    unsigned short* __restrict__ h1act, int N) {
    int node = blockIdx.x * 4 + (threadIdx.x >> 6);
    int lane = threadIdx.x & 63;
    if (node >= N) return;
    int hd = lane >> 3;
    int c = lane << 1;
    float ad8 = ad_n[node * 8 + (lane & 7)];
    float adv = ad_n[node * 8 + hd];
    int beg = row_start[node], end = row_start[node + 1];
    float ax = 0.f, ay = 0.f, denom = 0.f;
    int i = beg;
    for (; i + 3 < end; i += 4) {
        int s0 = sorted_src[i], s1 = sorted_src[i + 1];
        int s2 = sorted_src[i + 2], s3 = sorted_src[i + 3];
        int jj = (lane >> 3) & 3;
        int sj = (jj == 0) ? s0 : (jj == 1) ? s1 : (jj == 2) ? s2 : s3;
        float wall = expf(lrelu(as_n[sj * 8 + (lane & 7)] + ad8));
        float w0 = __shfl(wall, hd, 64);
        float w1 = __shfl(wall, 8 + hd, 64);
        float w2 = __shfl(wall, 16 + hd, 64);
        float w3 = __shfl(wall, 24 + hd, 64);
        unsigned v0 = *(const unsigned*)&h1g[(size_t)s0 * 128 + c];
        unsigned v1 = *(const unsigned*)&h1g[(size_t)s1 * 128 + c];
        unsigned v2 = *(const unsigned*)&h1g[(size_t)s2 * 128 + c];
        unsigned v3 = *(const unsigned*)&h1g[(size_t)s3 * 128 + c];
        ax += w0 * bf2f(v0 & 0xffffu) + w1 * bf2f(v1 & 0xffffu)
            + w2 * bf2f(v2 & 0xffffu) + w3 * bf2f(v3 & 0xffffu);
        ay += w0 * bf2f(v0 >> 16) + w1 * bf2f(v1 >> 16)
            + w2 * bf2f(v2 >> 16) + w3 * bf2f(v3 >> 16);
        denom += w0 + w1 + w2 + w3;
    }
    for (; i < end; i++) {
        int s0 = sorted_src[i];
        float w0 = expf(lrelu(as_n[s0 * 8 + hd] + adv));
        unsigned v0 = *(const unsigned*)&h1g[(size_t)s0 * 128 + c];
        ax += w0 * bf2f(v0 & 0xffffu);
        ay += w0 * bf2f(v0 >> 16);
        denom += w0;
    }
    float inv = 1.f / (denom + 1e-16f);
    float vx = ax * inv + b1[c];
    float vy = ay * inv + b1[c + 1];
    vx = (vx > 0.f) ? vx : (expf(vx) - 1.f);
    vy = (vy > 0.f) ? vy : (expf(vy) - 1.f);
    unsigned packed = (unsigned)f2bf(vx) | ((unsigned)f2bf(vy) << 16);
    *(unsigned*)&h1act[(size_t)node * 128 + c] = packed;
}

// ---------------- GEMM2 (MFMA) + fused alpha2 --------------------------------
// h2g[N,64](bf16) = h1act[N,128](bf16) @ W2[128,64]; also as_n/ad_n per row.
__global__ __launch_bounds__(256) void gemm2_kernel(
    const unsigned short* __restrict__ h1act, const float* __restrict__ W2,
    const float* __restrict__ a_s, const float* __restrict__ a_d,
    unsigned short* __restrict__ h2g, float* __restrict__ as_n,
    float* __restrict__ ad_n, int N) {
    __shared__ short Wt[64 * 136];    // Wt[n][k] bf16, padded
    int t = threadIdx.x;
    for (int id = t; id < 128 * 16; id += 256) {       // 2048 float4 loads
        int k = id >> 4;
        int n0 = (id & 15) * 4;
        float4 v = *(const float4*)&W2[k * 64 + n0];
        Wt[(n0 + 0) * 136 + k] = (short)f2bf(v.x);
        Wt[(n0 + 1) * 136 + k] = (short)f2bf(v.y);
        Wt[(n0 + 2) * 136 + k] = (short)f2bf(v.z);
        Wt[(n0 + 3) * 136 + k] = (short)f2bf(v.w);
    }
    __syncthreads();
    int wv = t >> 6, lane = t & 63;
    int m = lane & 15, q = lane >> 4;
    int row = blockIdx.x * 64 + wv * 16 + m;
    f32x4 acc[4];
#pragma unroll
    for (int j = 0; j < 4; j++) acc[j] = (f32x4){0.f, 0.f, 0.f, 0.f};
#pragma unroll
    for (int k0 = 0; k0 < 128; k0 += 32) {
        bf16x8 a = {0, 0, 0, 0, 0, 0, 0, 0};
        if (row < N) a = *(const bf16x8*)&h1act[(size_t)row * 128 + k0 + q * 8];
#pragma unroll
        for (int j = 0; j < 4; j++) {
            bf16x8 b = *(const bf16x8*)&Wt[(j * 16 + m) * 136 + k0 + q * 8];
            acc[j] = __builtin_amdgcn_mfma_f32_16x16x32_bf16(a, b, acc[j], 0, 0, 0);
        }
    }
    // epilogue: store h2g (bf16) + fused alpha2 row-dots
    float asl[4], adl[4];
#pragma unroll
    for (int j = 0; j < 4; j++) { asl[j] = a_s[j * 16 + m]; adl[j] = a_d[j * 16 + m]; }
    int rbase = blockIdx.x * 64 + wv * 16 + q * 4;
#pragma unroll
    for (int r = 0; r < 4; r++) {
        int rr = rbase + r;
        float s = 0.f, d = 0.f;
#pragma unroll
        for (int j = 0; j < 4; j++) {
            s += acc[j][r] * asl[j];
            d += acc[j][r] * adl[j];
        }
#pragma unroll
        for (int msk = 8; msk > 0; msk >>= 1) {
            s += __shfl_xor(s, msk, 64);
            d += __shfl_xor(d, msk, 64);
        }
        if (rr < N) {
            if (m == 0) { as_n[rr] = s; ad_n[rr] = d; }
#pragma unroll
            for (int j = 0; j < 4; j++)
                h2g[(size_t)rr * 64 + j * 16 + m] = f2bf(acc[j][r]);
        }
    }
}

// ---------------- layer-2 aggregation: one wave per dst node -----------------
__global__ __launch_bounds__(256) void agg2_kernel(
    const int* __restrict__ row_start, const int* __restrict__ sorted_src,
    const float* __restrict__ as_n, const float* __restrict__ ad_n,
    const unsigned short* __restrict__ h2g, const float* __restrict__ b2,
    float* __restrict__ out, int N) {
    int node = blockIdx.x * 4 + (threadIdx.x >> 6);
    int lane = threadIdx.x & 63;
    if (node >= N) return;
    float adv = ad_n[node];
    int beg = row_start[node], end = row_start[node + 1];
    float acc = 0.f, denom = 0.f;
    int i = beg;
    for (; i + 3 < end; i += 4) {
        int s0 = sorted_src[i], s1 = sorted_src[i + 1];
        int s2 = sorted_src[i + 2], s3 = sorted_src[i + 3];
        int jj = lane & 3;
        int sj = (jj == 0) ? s0 : (jj == 1) ? s1 : (jj == 2) ? s2 : s3;
        float wall = expf(lrelu(as_n[sj] + adv));
        float w0 = __shfl(wall, 0, 64);
        float w1 = __shfl(wall, 1, 64);
        float w2 = __shfl(wall, 2, 64);
        float w3 = __shfl(wall, 3, 64);
        acc += w0 * bf2f(h2g[(size_t)s0 * 64 + lane])
             + w1 * bf2f(h2g[(size_t)s1 * 64 + lane])
             + w2 * bf2f(h2g[(size_t)s2 * 64 + lane])
             + w3 * bf2f(h2g[(size_t)s3 * 64 + lane]);
        denom += w0 + w1 + w2 + w3;
    }
    for (; i < end; i++) {
        int s0 = sorted_src[i];
        float w0 = expf(lrelu(as_n[s0] + adv));
        acc += w0 * bf2f(h2g[(size_t)s0 * 64 + lane]);
        denom += w0;
    }
    float v = acc / (denom + 1e-16f) + b2[lane];
    float m = v;
#pragma unroll
    for (int s = 32; s > 0; s >>= 1) m = fmaxf(m, __shfl_xor(m, s, 64));
    float ex = expf(v - m);
#pragma unroll
    for (int s = 32; s > 0; s >>= 1) ex += __shfl_xor(ex, s, 64);
    out[(size_t)node * 64 + lane] = v - m - logf(ex);
}

extern "C" void kernel_launch(void* const* d_in, const int* in_sizes, int n_in,
                              void* d_out, int out_size, void* d_ws, size_t ws_size,
                              hipStream_t stream) {
    const float* x   = (const float*)d_in[0];
    const int*   idx = (const int*)d_in[1];
    const float* W1  = (const float*)d_in[2];
    const float* as1 = (const float*)d_in[3];
    const float* ad1 = (const float*)d_in[4];
    const float* b1  = (const float*)d_in[5];
    const float* W2  = (const float*)d_in[6];
    const float* as2 = (const float*)d_in[7];
    const float* ad2 = (const float*)d_in[8];
    const float* b2  = (const float*)d_in[9];
    float* out = (float*)d_out;

    const int N = in_sizes[0] / IN_DIM;
    const int E = in_sizes[1] / 2;
    const int EN = E + N;
    const int nb = (N + 1023) / 1024;

    // workspace layout (bf16 arrays first; all offsets 16B-aligned for N=50000)
    unsigned short* h1g   = (unsigned short*)d_ws;          // N*128 bf16
    unsigned short* h1act = h1g + (size_t)N * 128;          // N*128 bf16
    unsigned short* h2g   = h1act + (size_t)N * 128;        // N*64 bf16
    float* as1n = (float*)(h2g + (size_t)N * 64);           // N*8
    float* ad1n = as1n + (size_t)N * 8;                     // N*8
    float* as2n = ad1n + (size_t)N * 8;                     // N
    float* ad2n = as2n + (size_t)N;                         // N
    int* deg        = (int*)(ad2n + (size_t)N);             // N
    int* row_start  = deg + N;                              // N+1
    int* cursor     = row_start + N + 1;                    // N
    int* bsum       = cursor + N;                           // nb (<=1024)
    int* sorted_src = bsum + 1024;                          // E+N
    int* flag       = sorted_src + EN;                      // 1
    (void)ws_size; (void)n_in; (void)out_size;

    hipMemsetAsync(deg, 0, (size_t)N * sizeof(int), stream);

    detect_kernel<<<1, 64, 0, stream>>>(idx, flag);
    hist_kernel<<<(EN + 255) / 256, 256, 0, stream>>>(idx, flag, deg, E, N);
    scanA_kernel<<<nb, 256, 0, stream>>>(deg, row_start, bsum, N);
    scanB_kernel<<<1, 64, 0, stream>>>(bsum, nb);
    scanC_kernel<<<nb, 256, 0, stream>>>(row_start, cursor, bsum, N, EN);
    scatter_kernel<<<(EN + 255) / 256, 256, 0, stream>>>(idx, flag, cursor, sorted_src, E, N);

    gemm1_kernel<<<(N + 63) / 64, 256, 0, stream>>>(x, W1, h1g, N);
    alpha1_kernel<<<(N * 8 + 255) / 256, 256, 0, stream>>>(h1g, as1, ad1, as1n, ad1n, N);
    agg1_kernel<<<(N + 3) / 4, 256, 0, stream>>>(row_start, sorted_src, as1n, ad1n, h1g, b1, h1act, N);

    gemm2_kernel<<<(N + 63) / 64, 256, 0, stream>>>(h1act, W2, as2, ad2, h2g, as2n, ad2n, N);
    agg2_kernel<<<(N + 3) / 4, 256, 0, stream>>>(row_start, sorted_src, as2n, ad2n, h2g, b2, out, N);
}

// Round 5
// 257.808 us; speedup vs baseline: 4.7635x; 1.2289x over previous
//
#include <hip/hip_runtime.h>
#include <hip/hip_bf16.h>
#include <math.h>

#define IN_DIM 128
#define HID 128
#define HEADS 8
#define OUT_DIM 64
#define SLOPE 0.2f
#define BSHIFT 7          // 128 nodes per bucket
#define BCAP 4096         // entries per bucket (mean ~2176, +40 sigma headroom)
#define BCAPSHIFT 12
#define EPT 8             // edges per thread in bscatter

typedef short bf16x8 __attribute__((ext_vector_type(8)));
typedef float f32x4 __attribute__((ext_vector_type(4)));

__device__ __forceinline__ float lrelu(float x) { return fmaxf(x, SLOPE * x); }
__device__ __forceinline__ float bf2f(unsigned u) { return __uint_as_float(u << 16); }
__device__ __forceinline__ unsigned short f2bf(float f) {
    unsigned u = __float_as_uint(f);
    return (unsigned short)((u + 0x7FFF + ((u >> 16) & 1)) >> 16);  // RNE
}

// ---------------- dtype detection for edge_index (int32 vs int64 storage) ---
__global__ void detect_kernel(const int* __restrict__ idx, int* __restrict__ flag) {
    int lane = threadIdx.x;  // 64 threads
    int nz = 0;
    for (int i = 2 * lane + 1; i < 1024; i += 128) nz += (idx[i] != 0);
#pragma unroll
    for (int m = 32; m > 0; m >>= 1) nz += __shfl_xor(nz, m, 64);
    if (lane == 0) *flag = (nz > 16) ? 1 : 0;  // 1 => int32, 0 => int64
}

// ---------------- pass 1: block-aggregated bucket scatter --------------------
// Packs (dst&127)<<16 | src into per-bucket chunks reserved via one global
// atomic per (block,bucket). Write window = NB hot regions -> line locality.
__global__ __launch_bounds__(256) void bscatter_kernel(
    const int* __restrict__ idx, const int* __restrict__ flagp,
    int* __restrict__ gcursor, unsigned* __restrict__ bucket_buf,
    int E, int N, int NB) {
    __shared__ int hist[512];
    __shared__ int base[512];
    int t = threadIdx.x;
    for (int i = t; i < NB; i += 256) hist[i] = 0;
    __syncthreads();
    int e0 = blockIdx.x * (256 * EPT);
    int flag = *flagp;
    int EN = E + N;
    unsigned ent[EPT];
    int bid[EPT];
    int loc[EPT];
#pragma unroll
    for (int k = 0; k < EPT; k++) {
        int e = e0 + k * 256 + t;
        bid[k] = -1;
        if (e < EN) {
            int src, dst;
            if (e < E) {
                if (flag) { src = idx[e]; dst = idx[E + e]; }
                else      { src = idx[2 * e]; dst = idx[2 * (E + e)]; }
            } else {
                src = dst = e - E;
            }
            int b = dst >> BSHIFT;
            bid[k] = b;
            ent[k] = ((unsigned)(dst & ((1 << BSHIFT) - 1)) << 16) | (unsigned)src;
            loc[k] = atomicAdd(&hist[b], 1);
        }
    }
    __syncthreads();
    for (int i = t; i < NB; i += 256) {
        int c = hist[i];
        if (c) base[i] = atomicAdd(&gcursor[i], c);
    }
    __syncthreads();
#pragma unroll
    for (int k = 0; k < EPT; k++) {
        if (bid[k] >= 0) {
            int pos = base[bid[k]] + loc[k];
            if (pos < BCAP) bucket_buf[((size_t)bid[k] << BCAPSHIFT) + pos] = ent[k];
        }
    }
}

// ---------------- pass 2a: per-bucket histogram -> deg (coalesced writes) ----
__global__ __launch_bounds__(256) void bhist_kernel(
    const int* __restrict__ gcursor, const unsigned* __restrict__ bucket_buf,
    int* __restrict__ deg, int N) {
    __shared__ int cnt[128];
    int b = blockIdx.x, t = threadIdx.x;
    if (t < 128) cnt[t] = 0;
    __syncthreads();
    int c = min(gcursor[b], BCAP);
    const unsigned* buf = bucket_buf + ((size_t)b << BCAPSHIFT);
    for (int i = t; i < c; i += 256)
        atomicAdd(&cnt[(buf[i] >> 16) & 127], 1);
    __syncthreads();
    if (t < 128) {
        int node = (b << BSHIFT) + t;
        if (node < N) deg[node] = cnt[t];
    }
}

// ---------------- CSR build: multi-block exclusive scan ----------------------
__global__ __launch_bounds__(256) void scanA_kernel(
    const int* __restrict__ deg, int* __restrict__ row_start,
    int* __restrict__ bsum, int N) {
    __shared__ int wtot[4];
    int b = blockIdx.x, t = threadIdx.x;
    int base = b * 1024 + t * 4;
    int4 v = make_int4(0, 0, 0, 0);
    if (base + 3 < N) v = *(const int4*)&deg[base];
    else {
        if (base < N) v.x = deg[base];
        if (base + 1 < N) v.y = deg[base + 1];
        if (base + 2 < N) v.z = deg[base + 2];
        if (base + 3 < N) v.w = deg[base + 3];
    }
    int tsum = v.x + v.y + v.z + v.w;
    int lane = t & 63, wv = t >> 6;
    int incl = tsum;
#pragma unroll
    for (int off = 1; off < 64; off <<= 1) {
        int u = __shfl_up(incl, off, 64);
        if (lane >= off) incl += u;
    }
    if (lane == 63) wtot[wv] = incl;
    __syncthreads();
    int woff = 0;
    for (int k = 0; k < wv; k++) woff += wtot[k];
    int e0 = woff + incl - tsum;
    int e1 = e0 + v.x, e2 = e1 + v.y, e3 = e2 + v.z;
    if (base < N) row_start[base] = e0;
    if (base + 1 < N) row_start[base + 1] = e1;
    if (base + 2 < N) row_start[base + 2] = e2;
    if (base + 3 < N) row_start[base + 3] = e3;
    if (t == 255) bsum[b] = woff + incl;
}

__global__ void scanB_kernel(int* __restrict__ bsum, int nb) {
    int lane = threadIdx.x;  // 64
    int carry = 0;
    for (int base = 0; base < nb; base += 64) {
        int i = base + lane;
        int v = (i < nb) ? bsum[i] : 0;
        int incl = v;
#pragma unroll
        for (int off = 1; off < 64; off <<= 1) {
            int u = __shfl_up(incl, off, 64);
            if (lane >= off) incl += u;
        }
        if (i < nb) bsum[i] = carry + incl - v;
        carry += __shfl(incl, 63, 64);
    }
}

__global__ __launch_bounds__(256) void scanC_kernel(
    int* __restrict__ row_start, const int* __restrict__ bsum, int N, int total) {
    int b = blockIdx.x, t = threadIdx.x;
    int off = bsum[b];
    int base = b * 1024 + t * 4;
#pragma unroll
    for (int k = 0; k < 4; k++) {
        int i = base + k;
        if (i < N) row_start[i] += off;
    }
    if (b == 0 && t == 0) row_start[N] = total;
}

// ---------------- pass 2b: per-bucket counting sort -> sorted_src ------------
__global__ __launch_bounds__(256) void bsort_kernel(
    const int* __restrict__ gcursor, const unsigned* __restrict__ bucket_buf,
    const int* __restrict__ row_start, int* __restrict__ sorted_src, int N) {
    __shared__ int cur[128];
    int b = blockIdx.x, t = threadIdx.x;
    if (t < 128) {
        int node = (b << BSHIFT) + t;
        cur[t] = row_start[min(node, N)];
    }
    __syncthreads();
    int c = min(gcursor[b], BCAP);
    const unsigned* buf = bucket_buf + ((size_t)b << BCAPSHIFT);
    for (int i = t; i < c; i += 256) {
        unsigned e = buf[i];
        int pos = atomicAdd(&cur[(e >> 16) & 127], 1);
        sorted_src[pos] = (int)(e & 0xFFFFu);
    }
}

// ---------------- GEMM1 (MFMA): h1g[N,128](bf16) = x[N,128] @ W1[128,128] ----
__global__ __launch_bounds__(256) void gemm1_kernel(
    const float* __restrict__ x, const float* __restrict__ W1,
    unsigned short* __restrict__ h1g, int N) {
    __shared__ short Wt[128 * 136];   // Wt[n][k] bf16, rows padded to 136
    int t = threadIdx.x;
    for (int id = t; id < 128 * 32; id += 256) {
        int k = id >> 5;
        int n0 = (id & 31) * 4;
        float4 v = *(const float4*)&W1[k * 128 + n0];
        Wt[(n0 + 0) * 136 + k] = (short)f2bf(v.x);
        Wt[(n0 + 1) * 136 + k] = (short)f2bf(v.y);
        Wt[(n0 + 2) * 136 + k] = (short)f2bf(v.z);
        Wt[(n0 + 3) * 136 + k] = (short)f2bf(v.w);
    }
    __syncthreads();
    int wv = t >> 6, lane = t & 63;
    int m = lane & 15, q = lane >> 4;
    int row = blockIdx.x * 64 + wv * 16 + m;
    f32x4 acc[8];
#pragma unroll
    for (int j = 0; j < 8; j++) acc[j] = (f32x4){0.f, 0.f, 0.f, 0.f};
#pragma unroll
    for (int k0 = 0; k0 < 128; k0 += 32) {
        bf16x8 a = {0, 0, 0, 0, 0, 0, 0, 0};
        if (row < N) {
            const float* xp = &x[(size_t)row * 128 + k0 + q * 8];
            float4 u0 = *(const float4*)xp;
            float4 u1 = *(const float4*)(xp + 4);
            a[0] = (short)f2bf(u0.x); a[1] = (short)f2bf(u0.y);
            a[2] = (short)f2bf(u0.z); a[3] = (short)f2bf(u0.w);
            a[4] = (short)f2bf(u1.x); a[5] = (short)f2bf(u1.y);
            a[6] = (short)f2bf(u1.z); a[7] = (short)f2bf(u1.w);
        }
#pragma unroll
        for (int j = 0; j < 8; j++) {
            bf16x8 b = *(const bf16x8*)&Wt[(j * 16 + m) * 136 + k0 + q * 8];
            acc[j] = __builtin_amdgcn_mfma_f32_16x16x32_bf16(a, b, acc[j], 0, 0, 0);
        }
    }
    int rbase = blockIdx.x * 64 + wv * 16 + q * 4;
#pragma unroll
    for (int r = 0; r < 4; r++) {
        int rr = rbase + r;
        if (rr < N) {
#pragma unroll
            for (int j = 0; j < 8; j++)
                h1g[(size_t)rr * 128 + j * 16 + m] = f2bf(acc[j][r]);
        }
    }
}

// ---------------- per-node attention coefficients, layer 1 (bf16 h) ----------
__global__ void alpha1_kernel(const unsigned short* __restrict__ h1g,
                              const float* __restrict__ a_s, const float* __restrict__ a_d,
                              float* __restrict__ as_n, float* __restrict__ ad_n, int N) {
    int gid = blockIdx.x * blockDim.x + threadIdx.x;
    if (gid >= N * 8) return;
    int n = gid >> 3, hd = gid & 7;
    const uint4* hp = (const uint4*)(h1g + (size_t)n * 128 + hd * 16);
    uint4 u0 = hp[0], u1 = hp[1];
    unsigned uu[8] = {u0.x, u0.y, u0.z, u0.w, u1.x, u1.y, u1.z, u1.w};
    const float* sp = a_s + hd * 16;
    const float* dp = a_d + hd * 16;
    float s = 0.f, d = 0.f;
#pragma unroll
    for (int k = 0; k < 8; k++) {
        float lo = bf2f(uu[k] & 0xffffu), hi = bf2f(uu[k] >> 16);
        s += lo * sp[2 * k] + hi * sp[2 * k + 1];
        d += lo * dp[2 * k] + hi * dp[2 * k + 1];
    }
    as_n[gid] = s;
    ad_n[gid] = d;
}

// ---------------- layer-1 aggregation: one wave per dst node -----------------
__global__ __launch_bounds__(256) void agg1_kernel(
    const int* __restrict__ row_start, const int* __restrict__ sorted_src,
    const float* __restrict__ as_n, const float* __restrict__ ad_n,
    const unsigned short* __restrict__ h1g, const float* __restrict__ b1,
    unsigned short* __restrict__ h1act, int N) {
    int node = blockIdx.x * 4 + (threadIdx.x >> 6);
    int lane = threadIdx.x & 63;
    if (node >= N) return;
    int hd = lane >> 3;
    int c = lane << 1;
    float ad8 = ad_n[node * 8 + (lane & 7)];
    float adv = ad_n[node * 8 + hd];
    int beg = row_start[node], end = row_start[node + 1];
    float ax = 0.f, ay = 0.f, denom = 0.f;
    int i = beg;
    for (; i + 3 < end; i += 4) {
        int s0 = sorted_src[i], s1 = sorted_src[i + 1];
        int s2 = sorted_src[i + 2], s3 = sorted_src[i + 3];
        int jj = (lane >> 3) & 3;
        int sj = (jj == 0) ? s0 : (jj == 1) ? s1 : (jj == 2) ? s2 : s3;
        float wall = expf(lrelu(as_n[sj * 8 + (lane & 7)] + ad8));
        float w0 = __shfl(wall, hd, 64);
        float w1 = __shfl(wall, 8 + hd, 64);
        float w2 = __shfl(wall, 16 + hd, 64);
        float w3 = __shfl(wall, 24 + hd, 64);
        unsigned v0 = *(const unsigned*)&h1g[(size_t)s0 * 128 + c];
        unsigned v1 = *(const unsigned*)&h1g[(size_t)s1 * 128 + c];
        unsigned v2 = *(const unsigned*)&h1g[(size_t)s2 * 128 + c];
        unsigned v3 = *(const unsigned*)&h1g[(size_t)s3 * 128 + c];
        ax += w0 * bf2f(v0 & 0xffffu) + w1 * bf2f(v1 & 0xffffu)
            + w2 * bf2f(v2 & 0xffffu) + w3 * bf2f(v3 & 0xffffu);
        ay += w0 * bf2f(v0 >> 16) + w1 * bf2f(v1 >> 16)
            + w2 * bf2f(v2 >> 16) + w3 * bf2f(v3 >> 16);
        denom += w0 + w1 + w2 + w3;
    }
    for (; i < end; i++) {
        int s0 = sorted_src[i];
        float w0 = expf(lrelu(as_n[s0 * 8 + hd] + adv));
        unsigned v0 = *(const unsigned*)&h1g[(size_t)s0 * 128 + c];
        ax += w0 * bf2f(v0 & 0xffffu);
        ay += w0 * bf2f(v0 >> 16);
        denom += w0;
    }
    float inv = 1.f / (denom + 1e-16f);
    float vx = ax * inv + b1[c];
    float vy = ay * inv + b1[c + 1];
    vx = (vx > 0.f) ? vx : (expf(vx) - 1.f);
    vy = (vy > 0.f) ? vy : (expf(vy) - 1.f);
    unsigned packed = (unsigned)f2bf(vx) | ((unsigned)f2bf(vy) << 16);
    *(unsigned*)&h1act[(size_t)node * 128 + c] = packed;
}

// ---------------- GEMM2 (MFMA) + fused alpha2 --------------------------------
__global__ __launch_bounds__(256) void gemm2_kernel(
    const unsigned short* __restrict__ h1act, const float* __restrict__ W2,
    const float* __restrict__ a_s, const float* __restrict__ a_d,
    unsigned short* __restrict__ h2g, float* __restrict__ as_n,
    float* __restrict__ ad_n, int N) {
    __shared__ short Wt[64 * 136];
    int t = threadIdx.x;
    for (int id = t; id < 128 * 16; id += 256) {
        int k = id >> 4;
        int n0 = (id & 15) * 4;
        float4 v = *(const float4*)&W2[k * 64 + n0];
        Wt[(n0 + 0) * 136 + k] = (short)f2bf(v.x);
        Wt[(n0 + 1) * 136 + k] = (short)f2bf(v.y);
        Wt[(n0 + 2) * 136 + k] = (short)f2bf(v.z);
        Wt[(n0 + 3) * 136 + k] = (short)f2bf(v.w);
    }
    __syncthreads();
    int wv = t >> 6, lane = t & 63;
    int m = lane & 15, q = lane >> 4;
    int row = blockIdx.x * 64 + wv * 16 + m;
    f32x4 acc[4];
#pragma unroll
    for (int j = 0; j < 4; j++) acc[j] = (f32x4){0.f, 0.f, 0.f, 0.f};
#pragma unroll
    for (int k0 = 0; k0 < 128; k0 += 32) {
        bf16x8 a = {0, 0, 0, 0, 0, 0, 0, 0};
        if (row < N) a = *(const bf16x8*)&h1act[(size_t)row * 128 + k0 + q * 8];
#pragma unroll
        for (int j = 0; j < 4; j++) {
            bf16x8 b = *(const bf16x8*)&Wt[(j * 16 + m) * 136 + k0 + q * 8];
            acc[j] = __builtin_amdgcn_mfma_f32_16x16x32_bf16(a, b, acc[j], 0, 0, 0);
        }
    }
    float asl[4], adl[4];
#pragma unroll
    for (int j = 0; j < 4; j++) { asl[j] = a_s[j * 16 + m]; adl[j] = a_d[j * 16 + m]; }
    int rbase = blockIdx.x * 64 + wv * 16 + q * 4;
#pragma unroll
    for (int r = 0; r < 4; r++) {
        int rr = rbase + r;
        float s = 0.f, d = 0.f;
#pragma unroll
        for (int j = 0; j < 4; j++) {
            s += acc[j][r] * asl[j];
            d += acc[j][r] * adl[j];
        }
#pragma unroll
        for (int msk = 8; msk > 0; msk >>= 1) {
            s += __shfl_xor(s, msk, 64);
            d += __shfl_xor(d, msk, 64);
        }
        if (rr < N) {
            if (m == 0) { as_n[rr] = s; ad_n[rr] = d; }
#pragma unroll
            for (int j = 0; j < 4; j++)
                h2g[(size_t)rr * 64 + j * 16 + m] = f2bf(acc[j][r]);
        }
    }
}

// ---------------- layer-2 aggregation: one wave per dst node -----------------
__global__ __launch_bounds__(256) void agg2_kernel(
    const int* __restrict__ row_start, const int* __restrict__ sorted_src,
    const float* __restrict__ as_n, const float* __restrict__ ad_n,
    const unsigned short* __restrict__ h2g, const float* __restrict__ b2,
    float* __restrict__ out, int N) {
    int node = blockIdx.x * 4 + (threadIdx.x >> 6);
    int lane = threadIdx.x & 63;
    if (node >= N) return;
    float adv = ad_n[node];
    int beg = row_start[node], end = row_start[node + 1];
    float acc = 0.f, denom = 0.f;
    int i = beg;
    for (; i + 3 < end; i += 4) {
        int s0 = sorted_src[i], s1 = sorted_src[i + 1];
        int s2 = sorted_src[i + 2], s3 = sorted_src[i + 3];
        int jj = lane & 3;
        int sj = (jj == 0) ? s0 : (jj == 1) ? s1 : (jj == 2) ? s2 : s3;
        float wall = expf(lrelu(as_n[sj] + adv));
        float w0 = __shfl(wall, 0, 64);
        float w1 = __shfl(wall, 1, 64);
        float w2 = __shfl(wall, 2, 64);
        float w3 = __shfl(wall, 3, 64);
        acc += w0 * bf2f(h2g[(size_t)s0 * 64 + lane])
             + w1 * bf2f(h2g[(size_t)s1 * 64 + lane])
             + w2 * bf2f(h2g[(size_t)s2 * 64 + lane])
             + w3 * bf2f(h2g[(size_t)s3 * 64 + lane]);
        denom += w0 + w1 + w2 + w3;
    }
    for (; i < end; i++) {
        int s0 = sorted_src[i];
        float w0 = expf(lrelu(as_n[s0] + adv));
        acc += w0 * bf2f(h2g[(size_t)s0 * 64 + lane]);
        denom += w0;
    }
    float v = acc / (denom + 1e-16f) + b2[lane];
    float m = v;
#pragma unroll
    for (int s = 32; s > 0; s >>= 1) m = fmaxf(m, __shfl_xor(m, s, 64));
    float ex = expf(v - m);
#pragma unroll
    for (int s = 32; s > 0; s >>= 1) ex += __shfl_xor(ex, s, 64);
    out[(size_t)node * 64 + lane] = v - m - logf(ex);
}

extern "C" void kernel_launch(void* const* d_in, const int* in_sizes, int n_in,
                              void* d_out, int out_size, void* d_ws, size_t ws_size,
                              hipStream_t stream) {
    const float* x   = (const float*)d_in[0];
    const int*   idx = (const int*)d_in[1];
    const float* W1  = (const float*)d_in[2];
    const float* as1 = (const float*)d_in[3];
    const float* ad1 = (const float*)d_in[4];
    const float* b1  = (const float*)d_in[5];
    const float* W2  = (const float*)d_in[6];
    const float* as2 = (const float*)d_in[7];
    const float* ad2 = (const float*)d_in[8];
    const float* b2  = (const float*)d_in[9];
    float* out = (float*)d_out;

    const int N = in_sizes[0] / IN_DIM;
    const int E = in_sizes[1] / 2;
    const int EN = E + N;
    const int nb = (N + 1023) / 1024;
    const int NB = (N + (1 << BSHIFT) - 1) >> BSHIFT;   // buckets

    // workspace layout
    unsigned short* h1g   = (unsigned short*)d_ws;          // N*128 bf16
    unsigned short* h1act = h1g + (size_t)N * 128;          // N*128 bf16
    unsigned short* h2g   = h1act + (size_t)N * 128;        // N*64 bf16
    float* as1n = (float*)(h2g + (size_t)N * 64);           // N*8
    float* ad1n = as1n + (size_t)N * 8;                     // N*8
    float* as2n = ad1n + (size_t)N * 8;                     // N
    float* ad2n = as2n + (size_t)N;                         // N
    int* deg        = (int*)(ad2n + (size_t)N);             // N (16B-aligned)
    int* row_start  = deg + N;                              // N+1
    int* bsum       = row_start + N + 1;                    // 1024
    int* gcursor    = bsum + 1024;                          // 512
    unsigned* bucket_buf = (unsigned*)(gcursor + 512);      // NB*BCAP
    int* sorted_src = (int*)(bucket_buf + ((size_t)NB << BCAPSHIFT));  // E+N
    int* flag       = sorted_src + EN;                      // 1
    (void)ws_size; (void)n_in; (void)out_size;

    hipMemsetAsync(gcursor, 0, 512 * sizeof(int), stream);

    detect_kernel<<<1, 64, 0, stream>>>(idx, flag);
    bscatter_kernel<<<(EN + 256 * EPT - 1) / (256 * EPT), 256, 0, stream>>>(
        idx, flag, gcursor, bucket_buf, E, N, NB);
    bhist_kernel<<<NB, 256, 0, stream>>>(gcursor, bucket_buf, deg, N);
    scanA_kernel<<<nb, 256, 0, stream>>>(deg, row_start, bsum, N);
    scanB_kernel<<<1, 64, 0, stream>>>(bsum, nb);
    scanC_kernel<<<nb, 256, 0, stream>>>(row_start, bsum, N, EN);
    bsort_kernel<<<NB, 256, 0, stream>>>(gcursor, bucket_buf, row_start, sorted_src, N);

    gemm1_kernel<<<(N + 63) / 64, 256, 0, stream>>>(x, W1, h1g, N);
    alpha1_kernel<<<(N * 8 + 255) / 256, 256, 0, stream>>>(h1g, as1, ad1, as1n, ad1n, N);
    agg1_kernel<<<(N + 3) / 4, 256, 0, stream>>>(row_start, sorted_src, as1n, ad1n, h1g, b1, h1act, N);

    gemm2_kernel<<<(N + 63) / 64, 256, 0, stream>>>(h1act, W2, as2, ad2, h2g, as2n, ad2n, N);
    agg2_kernel<<<(N + 3) / 4, 256, 0, stream>>>(row_start, sorted_src, as2n, ad2n, h2g, b2, out, N);
}

// Round 6
// 240.089 us; speedup vs baseline: 5.1150x; 1.0738x over previous
//
#include <hip/hip_runtime.h>
#include <hip/hip_bf16.h>
#include <math.h>

#define IN_DIM 128
#define HID 128
#define HEADS 8
#define OUT_DIM 64
#define SLOPE 0.2f
#define BSHIFT 7          // 128 nodes per bucket
#define BCAP 4096         // entries per bucket (mean ~2176, +40 sigma headroom)
#define BCAPSHIFT 12
#define EPT 8             // edges per thread in bscatter

typedef short bf16x8 __attribute__((ext_vector_type(8)));
typedef float f32x4 __attribute__((ext_vector_type(4)));

__device__ __forceinline__ float lrelu(float x) { return fmaxf(x, SLOPE * x); }
__device__ __forceinline__ float bf2f(unsigned u) { return __uint_as_float(u << 16); }
__device__ __forceinline__ unsigned short f2bf(float f) {
    unsigned u = __float_as_uint(f);
    return (unsigned short)((u + 0x7FFF + ((u >> 16) & 1)) >> 16);  // RNE
}

// ---------------- pass 1: block-aggregated bucket scatter (detect inlined) ---
__global__ __launch_bounds__(256) void bscatter_kernel(
    const int* __restrict__ idx,
    int* __restrict__ gcursor, unsigned* __restrict__ bucket_buf,
    int E, int N, int NB) {
    __shared__ int hist[512];
    __shared__ int base[512];
    __shared__ int s_nz;
    int t = threadIdx.x;
    for (int i = t; i < NB; i += 256) hist[i] = 0;
    if (t == 0) s_nz = 0;
    __syncthreads();
    // inline dtype detection: odd int32 words nonzero => int32 storage
    {
        int nz = (idx[2 * t + 1] != 0) + (idx[2 * t + 513] != 0);
        if (nz) atomicAdd(&s_nz, nz);
    }
    __syncthreads();
    int flag = (s_nz > 16) ? 1 : 0;   // 1 => int32, 0 => int64 storage
    int e0 = blockIdx.x * (256 * EPT);
    int EN = E + N;
    unsigned ent[EPT];
    int bid[EPT];
    int loc[EPT];
#pragma unroll
    for (int k = 0; k < EPT; k++) {
        int e = e0 + k * 256 + t;
        bid[k] = -1;
        if (e < EN) {
            int src, dst;
            if (e < E) {
                if (flag) { src = idx[e]; dst = idx[E + e]; }
                else      { src = idx[2 * e]; dst = idx[2 * (E + e)]; }
            } else {
                src = dst = e - E;
            }
            int b = dst >> BSHIFT;
            bid[k] = b;
            ent[k] = ((unsigned)(dst & ((1 << BSHIFT) - 1)) << 16) | (unsigned)src;
            loc[k] = atomicAdd(&hist[b], 1);
        }
    }
    __syncthreads();
    for (int i = t; i < NB; i += 256) {
        int c = hist[i];
        if (c) base[i] = atomicAdd(&gcursor[i], c);
    }
    __syncthreads();
#pragma unroll
    for (int k = 0; k < EPT; k++) {
        if (bid[k] >= 0) {
            int pos = base[bid[k]] + loc[k];
            if (pos < BCAP) bucket_buf[((size_t)bid[k] << BCAPSHIFT) + pos] = ent[k];
        }
    }
}

// ---------------- bucket-base exclusive scan (1 wave, NB<=512) ---------------
__global__ void bucketscan_kernel(const int* __restrict__ gcursor,
                                  int* __restrict__ bbase, int nb) {
    int lane = threadIdx.x;  // 64
    int carry = 0;
    for (int base = 0; base < nb; base += 64) {
        int i = base + lane;
        int v = (i < nb) ? min(gcursor[i], BCAP) : 0;
        int incl = v;
#pragma unroll
        for (int off = 1; off < 64; off <<= 1) {
            int u = __shfl_up(incl, off, 64);
            if (lane >= off) incl += u;
        }
        if (i < nb) bbase[i] = carry + incl - v;
        carry += __shfl(incl, 63, 64);
    }
}

// ---------------- pass 2: per-bucket hist + scan + row_start + counting sort -
__global__ __launch_bounds__(256) void bsort_kernel(
    const int* __restrict__ gcursor, const int* __restrict__ bbase,
    const unsigned* __restrict__ bucket_buf,
    int* __restrict__ row_start, int* __restrict__ sorted_src, int N) {
    __shared__ int cnt[128];
    __shared__ int cur[128];
    __shared__ int s_w0;
    int b = blockIdx.x, t = threadIdx.x;
    if (t < 128) cnt[t] = 0;
    __syncthreads();
    int c = min(gcursor[b], BCAP);
    const unsigned* buf = bucket_buf + ((size_t)b << BCAPSHIFT);
    for (int i = t; i < c; i += 256)
        atomicAdd(&cnt[(buf[i] >> 16) & 127], 1);
    __syncthreads();
    // exclusive scan over cnt[0..127] with waves 0 and 1
    int v = (t < 128) ? cnt[t] : 0;
    int lane = t & 63;
    int incl = v;
#pragma unroll
    for (int off = 1; off < 64; off <<= 1) {
        int u = __shfl_up(incl, off, 64);
        if (lane >= off) incl += u;
    }
    if (t == 63) s_w0 = incl;
    __syncthreads();
    if (t < 128) {
        int excl = incl - v + ((t >= 64) ? s_w0 : 0);
        int pos = bbase[b] + excl;
        cur[t] = pos;
        int node = (b << BSHIFT) + t;
        if (node <= N) row_start[node] = pos;
    }
    __syncthreads();
    for (int i = t; i < c; i += 256) {
        unsigned e = buf[i];
        int pos = atomicAdd(&cur[(e >> 16) & 127], 1);
        sorted_src[pos] = (int)(e & 0xFFFFu);
    }
}

// ---------------- GEMM1 (MFMA): h1g[N,128](bf16) = x[N,128] @ W1[128,128] ----
__global__ __launch_bounds__(256) void gemm1_kernel(
    const float* __restrict__ x, const float* __restrict__ W1,
    unsigned short* __restrict__ h1g, int N) {
    __shared__ short Wt[128 * 136];   // Wt[n][k] bf16, rows padded to 136
    int t = threadIdx.x;
    for (int id = t; id < 128 * 32; id += 256) {
        int k = id >> 5;
        int n0 = (id & 31) * 4;
        float4 v = *(const float4*)&W1[k * 128 + n0];
        Wt[(n0 + 0) * 136 + k] = (short)f2bf(v.x);
        Wt[(n0 + 1) * 136 + k] = (short)f2bf(v.y);
        Wt[(n0 + 2) * 136 + k] = (short)f2bf(v.z);
        Wt[(n0 + 3) * 136 + k] = (short)f2bf(v.w);
    }
    __syncthreads();
    int wv = t >> 6, lane = t & 63;
    int m = lane & 15, q = lane >> 4;
    int row = blockIdx.x * 64 + wv * 16 + m;
    f32x4 acc[8];
#pragma unroll
    for (int j = 0; j < 8; j++) acc[j] = (f32x4){0.f, 0.f, 0.f, 0.f};
#pragma unroll
    for (int k0 = 0; k0 < 128; k0 += 32) {
        bf16x8 a = {0, 0, 0, 0, 0, 0, 0, 0};
        if (row < N) {
            const float* xp = &x[(size_t)row * 128 + k0 + q * 8];
            float4 u0 = *(const float4*)xp;
            float4 u1 = *(const float4*)(xp + 4);
            a[0] = (short)f2bf(u0.x); a[1] = (short)f2bf(u0.y);
            a[2] = (short)f2bf(u0.z); a[3] = (short)f2bf(u0.w);
            a[4] = (short)f2bf(u1.x); a[5] = (short)f2bf(u1.y);
            a[6] = (short)f2bf(u1.z); a[7] = (short)f2bf(u1.w);
        }
#pragma unroll
        for (int j = 0; j < 8; j++) {
            bf16x8 b = *(const bf16x8*)&Wt[(j * 16 + m) * 136 + k0 + q * 8];
            acc[j] = __builtin_amdgcn_mfma_f32_16x16x32_bf16(a, b, acc[j], 0, 0, 0);
        }
    }
    int rbase = blockIdx.x * 64 + wv * 16 + q * 4;
#pragma unroll
    for (int r = 0; r < 4; r++) {
        int rr = rbase + r;
        if (rr < N) {
#pragma unroll
            for (int j = 0; j < 8; j++)
                h1g[(size_t)rr * 128 + j * 16 + m] = f2bf(acc[j][r]);
        }
    }
}

// ---------------- per-node attention coefficients, layer 1 (bf16 h) ----------
__global__ void alpha1_kernel(const unsigned short* __restrict__ h1g,
                              const float* __restrict__ a_s, const float* __restrict__ a_d,
                              float* __restrict__ as_n, float* __restrict__ ad_n, int N) {
    int gid = blockIdx.x * blockDim.x + threadIdx.x;
    if (gid >= N * 8) return;
    int n = gid >> 3, hd = gid & 7;
    const uint4* hp = (const uint4*)(h1g + (size_t)n * 128 + hd * 16);
    uint4 u0 = hp[0], u1 = hp[1];
    unsigned uu[8] = {u0.x, u0.y, u0.z, u0.w, u1.x, u1.y, u1.z, u1.w};
    const float* sp = a_s + hd * 16;
    const float* dp = a_d + hd * 16;
    float s = 0.f, d = 0.f;
#pragma unroll
    for (int k = 0; k < 8; k++) {
        float lo = bf2f(uu[k] & 0xffffu), hi = bf2f(uu[k] >> 16);
        s += lo * sp[2 * k] + hi * sp[2 * k + 1];
        d += lo * dp[2 * k] + hi * dp[2 * k + 1];
    }
    as_n[gid] = s;
    ad_n[gid] = d;
}

// ---------------- layer-1 aggregation: wave/node, slot x channel-group -------
// lane = slot(2b) x cg(4b): slot handles edge i+slot, cg handles 8 channels.
__global__ __launch_bounds__(256) void agg1_kernel(
    const int* __restrict__ row_start, const int* __restrict__ sorted_src,
    const float* __restrict__ as_n, const float* __restrict__ ad_n,
    const unsigned short* __restrict__ h1g, const float* __restrict__ b1,
    unsigned short* __restrict__ h1act, int N) {
    int node = blockIdx.x * 4 + (threadIdx.x >> 6);
    int lane = threadIdx.x & 63;
    if (node >= N) return;
    int slot = lane >> 4, cg = lane & 15;
    int srcLane = (slot << 3) | (cg >> 1);     // weight source: slot*8 + head
    float ad_w = ad_n[node * 8 + (lane & 7)];  // for weight-computing role
    int beg = row_start[node], end = row_start[node + 1];
    float acc[8];
#pragma unroll
    for (int k = 0; k < 8; k++) acc[k] = 0.f;
    float denom = 0.f;
    for (int i = beg; i < end; i += 4) {
        // weight role: wslot = (lane>>3)&3, whead = lane&7 (dup across halves)
        int ew = i + ((lane >> 3) & 3);
        int sw = sorted_src[min(ew, end - 1)];
        float w = __expf(lrelu(as_n[sw * 8 + (lane & 7)] + ad_w));
        w = (ew < end) ? w : 0.f;
        float wv = __shfl(w, srcLane, 64);
        // gather role: 8 channels of edge i+slot
        int eg = i + slot;
        int sg = sorted_src[min(eg, end - 1)];
        uint4 hv = *(const uint4*)&h1g[(size_t)sg * 128 + cg * 8];
        acc[0] += wv * bf2f(hv.x & 0xffffu); acc[1] += wv * bf2f(hv.x >> 16);
        acc[2] += wv * bf2f(hv.y & 0xffffu); acc[3] += wv * bf2f(hv.y >> 16);
        acc[4] += wv * bf2f(hv.z & 0xffffu); acc[5] += wv * bf2f(hv.z >> 16);
        acc[6] += wv * bf2f(hv.w & 0xffffu); acc[7] += wv * bf2f(hv.w >> 16);
        denom += wv;
    }
    // reduce over the 4 slots (lanes differing in bits 4-5)
#pragma unroll
    for (int msk = 16; msk < 64; msk <<= 1) {
#pragma unroll
        for (int k = 0; k < 8; k++) acc[k] += __shfl_xor(acc[k], msk, 64);
        denom += __shfl_xor(denom, msk, 64);
    }
    if (slot == 0) {
        float inv = 1.f / (denom + 1e-16f);
        int c0 = cg * 8;
        unsigned ow[4];
#pragma unroll
        for (int p = 0; p < 4; p++) {
            float v0 = acc[2 * p] * inv + b1[c0 + 2 * p];
            float v1 = acc[2 * p + 1] * inv + b1[c0 + 2 * p + 1];
            v0 = (v0 > 0.f) ? v0 : (__expf(v0) - 1.f);
            v1 = (v1 > 0.f) ? v1 : (__expf(v1) - 1.f);
            ow[p] = (unsigned)f2bf(v0) | ((unsigned)f2bf(v1) << 16);
        }
        *(uint4*)&h1act[(size_t)node * 128 + c0] = make_uint4(ow[0], ow[1], ow[2], ow[3]);
    }
}

// ---------------- GEMM2 (MFMA) + fused alpha2 --------------------------------
__global__ __launch_bounds__(256) void gemm2_kernel(
    const unsigned short* __restrict__ h1act, const float* __restrict__ W2,
    const float* __restrict__ a_s, const float* __restrict__ a_d,
    unsigned short* __restrict__ h2g, float* __restrict__ as_n,
    float* __restrict__ ad_n, int N) {
    __shared__ short Wt[64 * 136];
    int t = threadIdx.x;
    for (int id = t; id < 128 * 16; id += 256) {
        int k = id >> 4;
        int n0 = (id & 15) * 4;
        float4 v = *(const float4*)&W2[k * 64 + n0];
        Wt[(n0 + 0) * 136 + k] = (short)f2bf(v.x);
        Wt[(n0 + 1) * 136 + k] = (short)f2bf(v.y);
        Wt[(n0 + 2) * 136 + k] = (short)f2bf(v.z);
        Wt[(n0 + 3) * 136 + k] = (short)f2bf(v.w);
    }
    __syncthreads();
    int wv = t >> 6, lane = t & 63;
    int m = lane & 15, q = lane >> 4;
    int row = blockIdx.x * 64 + wv * 16 + m;
    f32x4 acc[4];
#pragma unroll
    for (int j = 0; j < 4; j++) acc[j] = (f32x4){0.f, 0.f, 0.f, 0.f};
#pragma unroll
    for (int k0 = 0; k0 < 128; k0 += 32) {
        bf16x8 a = {0, 0, 0, 0, 0, 0, 0, 0};
        if (row < N) a = *(const bf16x8*)&h1act[(size_t)row * 128 + k0 + q * 8];
#pragma unroll
        for (int j = 0; j < 4; j++) {
            bf16x8 b = *(const bf16x8*)&Wt[(j * 16 + m) * 136 + k0 + q * 8];
            acc[j] = __builtin_amdgcn_mfma_f32_16x16x32_bf16(a, b, acc[j], 0, 0, 0);
        }
    }
    float asl[4], adl[4];
#pragma unroll
    for (int j = 0; j < 4; j++) { asl[j] = a_s[j * 16 + m]; adl[j] = a_d[j * 16 + m]; }
    int rbase = blockIdx.x * 64 + wv * 16 + q * 4;
#pragma unroll
    for (int r = 0; r < 4; r++) {
        int rr = rbase + r;
        float s = 0.f, d = 0.f;
#pragma unroll
        for (int j = 0; j < 4; j++) {
            s += acc[j][r] * asl[j];
            d += acc[j][r] * adl[j];
        }
#pragma unroll
        for (int msk = 8; msk > 0; msk >>= 1) {
            s += __shfl_xor(s, msk, 64);
            d += __shfl_xor(d, msk, 64);
        }
        if (rr < N) {
            if (m == 0) { as_n[rr] = s; ad_n[rr] = d; }
#pragma unroll
            for (int j = 0; j < 4; j++)
                h2g[(size_t)rr * 64 + j * 16 + m] = f2bf(acc[j][r]);
        }
    }
}

// ---------------- layer-2 aggregation + log_softmax: wave/node ---------------
// lane = slot(2b) x cg(4b): slot handles edge i+slot, cg handles 4 channels.
__global__ __launch_bounds__(256) void agg2_kernel(
    const int* __restrict__ row_start, const int* __restrict__ sorted_src,
    const float* __restrict__ as_n, const float* __restrict__ ad_n,
    const unsigned short* __restrict__ h2g, const float* __restrict__ b2,
    float* __restrict__ out, int N) {
    int node = blockIdx.x * 4 + (threadIdx.x >> 6);
    int lane = threadIdx.x & 63;
    if (node >= N) return;
    int slot = lane >> 4, cg = lane & 15;
    float adv = ad_n[node];
    int beg = row_start[node], end = row_start[node + 1];
    float acc[4];
#pragma unroll
    for (int k = 0; k < 4; k++) acc[k] = 0.f;
    float denom = 0.f;
    for (int i = beg; i < end; i += 4) {
        int ew = i + (lane & 3);
        int sw = sorted_src[min(ew, end - 1)];
        float w = __expf(lrelu(as_n[sw] + adv));
        w = (ew < end) ? w : 0.f;
        float wv = __shfl(w, slot, 64);
        int eg = i + slot;
        int sg = sorted_src[min(eg, end - 1)];
        uint2 hv = *(const uint2*)&h2g[(size_t)sg * 64 + cg * 4];
        acc[0] += wv * bf2f(hv.x & 0xffffu); acc[1] += wv * bf2f(hv.x >> 16);
        acc[2] += wv * bf2f(hv.y & 0xffffu); acc[3] += wv * bf2f(hv.y >> 16);
        denom += wv;
    }
#pragma unroll
    for (int msk = 16; msk < 64; msk <<= 1) {
#pragma unroll
        for (int k = 0; k < 4; k++) acc[k] += __shfl_xor(acc[k], msk, 64);
        denom += __shfl_xor(denom, msk, 64);
    }
    if (slot == 0) {
        float inv = 1.f / (denom + 1e-16f);
        int c0 = cg * 4;
        float v[4];
#pragma unroll
        for (int k = 0; k < 4; k++) v[k] = acc[k] * inv + b2[c0 + k];
        float m = fmaxf(fmaxf(v[0], v[1]), fmaxf(v[2], v[3]));
#pragma unroll
        for (int msk = 8; msk > 0; msk >>= 1) m = fmaxf(m, __shfl_xor(m, msk, 64));
        float ex = __expf(v[0] - m) + __expf(v[1] - m) + __expf(v[2] - m) + __expf(v[3] - m);
#pragma unroll
        for (int msk = 8; msk > 0; msk >>= 1) ex += __shfl_xor(ex, msk, 64);
        float lse = m + __logf(ex);
        float4 ov = make_float4(v[0] - lse, v[1] - lse, v[2] - lse, v[3] - lse);
        *(float4*)&out[(size_t)node * 64 + c0] = ov;
    }
}

extern "C" void kernel_launch(void* const* d_in, const int* in_sizes, int n_in,
                              void* d_out, int out_size, void* d_ws, size_t ws_size,
                              hipStream_t stream) {
    const float* x   = (const float*)d_in[0];
    const int*   idx = (const int*)d_in[1];
    const float* W1  = (const float*)d_in[2];
    const float* as1 = (const float*)d_in[3];
    const float* ad1 = (const float*)d_in[4];
    const float* b1  = (const float*)d_in[5];
    const float* W2  = (const float*)d_in[6];
    const float* as2 = (const float*)d_in[7];
    const float* ad2 = (const float*)d_in[8];
    const float* b2  = (const float*)d_in[9];
    float* out = (float*)d_out;

    const int N = in_sizes[0] / IN_DIM;
    const int E = in_sizes[1] / 2;
    const int EN = E + N;
    const int NB = (N + (1 << BSHIFT) - 1) >> BSHIFT;   // buckets

    // workspace layout
    unsigned short* h1g   = (unsigned short*)d_ws;          // N*128 bf16
    unsigned short* h1act = h1g + (size_t)N * 128;          // N*128 bf16
    unsigned short* h2g   = h1act + (size_t)N * 128;        // N*64 bf16
    float* as1n = (float*)(h2g + (size_t)N * 64);           // N*8
    float* ad1n = as1n + (size_t)N * 8;                     // N*8
    float* as2n = ad1n + (size_t)N * 8;                     // N
    float* ad2n = as2n + (size_t)N;                         // N
    int* row_start  = (int*)(ad2n + (size_t)N);             // N+1
    int* gcursor    = row_start + N + 1;                    // 512
    int* bbase      = gcursor + 512;                        // 512
    unsigned* bucket_buf = (unsigned*)(bbase + 512);        // NB*BCAP
    int* sorted_src = (int*)(bucket_buf + ((size_t)NB << BCAPSHIFT));  // E+N
    (void)ws_size; (void)n_in; (void)out_size;

    hipMemsetAsync(gcursor, 0, 512 * sizeof(int), stream);

    bscatter_kernel<<<(EN + 256 * EPT - 1) / (256 * EPT), 256, 0, stream>>>(
        idx, gcursor, bucket_buf, E, N, NB);
    bucketscan_kernel<<<1, 64, 0, stream>>>(gcursor, bbase, NB);
    bsort_kernel<<<NB, 256, 0, stream>>>(gcursor, bbase, bucket_buf, row_start, sorted_src, N);

    gemm1_kernel<<<(N + 63) / 64, 256, 0, stream>>>(x, W1, h1g, N);
    alpha1_kernel<<<(N * 8 + 255) / 256, 256, 0, stream>>>(h1g, as1, ad1, as1n, ad1n, N);
    agg1_kernel<<<(N + 3) / 4, 256, 0, stream>>>(row_start, sorted_src, as1n, ad1n, h1g, b1, h1act, N);

    gemm2_kernel<<<(N + 63) / 64, 256, 0, stream>>>(h1act, W2, as2, ad2, h2g, as2n, ad2n, N);
    agg2_kernel<<<(N + 3) / 4, 256, 0, stream>>>(row_start, sorted_src, as2n, ad2n, h2g, b2, out, N);
}

// Round 7
// 217.898 us; speedup vs baseline: 5.6359x; 1.1018x over previous
//
#include <hip/hip_runtime.h>
#include <hip/hip_bf16.h>
#include <math.h>

#define IN_DIM 128
#define HID 128
#define HEADS 8
#define OUT_DIM 64
#define SLOPE 0.2f
#define BSHIFT 7          // 128 nodes per bucket
#define BCAP 4096         // entries per bucket (mean ~2176)
#define BCAPSHIFT 12
#define EPT 8             // edges per thread in bscatter

typedef short bf16x8 __attribute__((ext_vector_type(8)));
typedef float f32x4 __attribute__((ext_vector_type(4)));

__device__ __forceinline__ float lrelu(float x) { return fmaxf(x, SLOPE * x); }
__device__ __forceinline__ float bf2f(unsigned u) { return __uint_as_float(u << 16); }
__device__ __forceinline__ unsigned short f2bf(float f) {
    unsigned u = __float_as_uint(f);
    return (unsigned short)((u + 0x7FFF + ((u >> 16) & 1)) >> 16);  // RNE
}

// ---------------- K1 path A: block-aggregated bucket scatter -----------------
__device__ __forceinline__ void bscatter_body(
    int blk, const int* __restrict__ idx,
    int* __restrict__ gcursor, unsigned* __restrict__ bucket_buf,
    int E, int N, int NB) {
    __shared__ int hist[512];
    __shared__ int base[512];
    __shared__ int s_nz;
    int t = threadIdx.x;
    for (int i = t; i < NB; i += 256) hist[i] = 0;
    if (t == 0) s_nz = 0;
    __syncthreads();
    // inline dtype detection: odd int32 words nonzero => int32 storage
    {
        int nz = (idx[2 * t + 1] != 0) + (idx[2 * t + 513] != 0);
        if (nz) atomicAdd(&s_nz, nz);
    }
    __syncthreads();
    int flag = (s_nz > 16) ? 1 : 0;   // 1 => int32, 0 => int64 storage
    int e0 = blk * (256 * EPT);
    int EN = E + N;
    unsigned ent[EPT];
    int bid[EPT];
    int loc[EPT];
#pragma unroll
    for (int k = 0; k < EPT; k++) {
        int e = e0 + k * 256 + t;
        bid[k] = -1;
        if (e < EN) {
            int src, dst;
            if (e < E) {
                if (flag) { src = idx[e]; dst = idx[E + e]; }
                else      { src = idx[2 * e]; dst = idx[2 * (E + e)]; }
            } else {
                src = dst = e - E;
            }
            int b = dst >> BSHIFT;
            bid[k] = b;
            ent[k] = ((unsigned)(dst & ((1 << BSHIFT) - 1)) << 16) | (unsigned)src;
            loc[k] = atomicAdd(&hist[b], 1);
        }
    }
    __syncthreads();
    for (int i = t; i < NB; i += 256) {
        int c = hist[i];
        if (c) base[i] = atomicAdd(&gcursor[i], c);
    }
    __syncthreads();
#pragma unroll
    for (int k = 0; k < EPT; k++) {
        if (bid[k] >= 0) {
            int pos = base[bid[k]] + loc[k];
            if (pos < BCAP) bucket_buf[((size_t)bid[k] << BCAPSHIFT) + pos] = ent[k];
        }
    }
}

// ---------------- K1 path B: MFMA GEMM1 --------------------------------------
__device__ __forceinline__ void gemm1_body(
    int blk, const float* __restrict__ x, const float* __restrict__ W1,
    unsigned short* __restrict__ h1g, int N) {
    __shared__ short Wt[128 * 136];   // Wt[n][k] bf16, rows padded to 136
    int t = threadIdx.x;
    for (int id = t; id < 128 * 32; id += 256) {
        int k = id >> 5;
        int n0 = (id & 31) * 4;
        float4 v = *(const float4*)&W1[k * 128 + n0];
        Wt[(n0 + 0) * 136 + k] = (short)f2bf(v.x);
        Wt[(n0 + 1) * 136 + k] = (short)f2bf(v.y);
        Wt[(n0 + 2) * 136 + k] = (short)f2bf(v.z);
        Wt[(n0 + 3) * 136 + k] = (short)f2bf(v.w);
    }
    __syncthreads();
    int wv = t >> 6, lane = t & 63;
    int m = lane & 15, q = lane >> 4;
    int row = blk * 64 + wv * 16 + m;
    f32x4 acc[8];
#pragma unroll
    for (int j = 0; j < 8; j++) acc[j] = (f32x4){0.f, 0.f, 0.f, 0.f};
#pragma unroll
    for (int k0 = 0; k0 < 128; k0 += 32) {
        bf16x8 a = {0, 0, 0, 0, 0, 0, 0, 0};
        if (row < N) {
            const float* xp = &x[(size_t)row * 128 + k0 + q * 8];
            float4 u0 = *(const float4*)xp;
            float4 u1 = *(const float4*)(xp + 4);
            a[0] = (short)f2bf(u0.x); a[1] = (short)f2bf(u0.y);
            a[2] = (short)f2bf(u0.z); a[3] = (short)f2bf(u0.w);
            a[4] = (short)f2bf(u1.x); a[5] = (short)f2bf(u1.y);
            a[6] = (short)f2bf(u1.z); a[7] = (short)f2bf(u1.w);
        }
#pragma unroll
        for (int j = 0; j < 8; j++) {
            bf16x8 b = *(const bf16x8*)&Wt[(j * 16 + m) * 136 + k0 + q * 8];
            acc[j] = __builtin_amdgcn_mfma_f32_16x16x32_bf16(a, b, acc[j], 0, 0, 0);
        }
    }
    int rbase = blk * 64 + wv * 16 + q * 4;
#pragma unroll
    for (int r = 0; r < 4; r++) {
        int rr = rbase + r;
        if (rr < N) {
#pragma unroll
            for (int j = 0; j < 8; j++)
                h1g[(size_t)rr * 128 + j * 16 + m] = f2bf(acc[j][r]);
        }
    }
}

__global__ __launch_bounds__(256) void k1_kernel(
    const int* __restrict__ idx, int* __restrict__ gcursor,
    unsigned* __restrict__ bucket_buf,
    const float* __restrict__ x, const float* __restrict__ W1,
    unsigned short* __restrict__ h1g, int E, int N, int NB, int GS) {
    if ((int)blockIdx.x < GS)
        bscatter_body(blockIdx.x, idx, gcursor, bucket_buf, E, N, NB);
    else
        gemm1_body(blockIdx.x - GS, x, W1, h1g, N);
}

// ---------------- K2 path A: per-bucket sort (inline bucket-base scan) -------
__device__ __forceinline__ void bsort_body(
    int b, const int* __restrict__ gcursor, const unsigned* __restrict__ bucket_buf,
    int* __restrict__ row_start, int* __restrict__ sorted_src, int N, int NB) {
    __shared__ int cnt[128];
    __shared__ int cur[128];
    __shared__ int red[4];
    __shared__ int s_w0;
    int t = threadIdx.x;
    if (t < 128) cnt[t] = 0;
    // inline exclusive scan over buckets: bbase = sum_{i<b} min(gcursor[i],BCAP)
    int partial = 0;
    for (int i = t; i < b; i += 256) partial += min(gcursor[i], BCAP);
#pragma unroll
    for (int msk = 32; msk > 0; msk >>= 1) partial += __shfl_xor(partial, msk, 64);
    if ((t & 63) == 0) red[t >> 6] = partial;
    __syncthreads();
    int bbase = red[0] + red[1] + red[2] + red[3];
    int c = min(gcursor[b], BCAP);
    const unsigned* buf = bucket_buf + ((size_t)b << BCAPSHIFT);
    for (int i = t; i < c; i += 256)
        atomicAdd(&cnt[(buf[i] >> 16) & 127], 1);
    __syncthreads();
    // exclusive scan over cnt[0..127] with waves 0 and 1
    int v = (t < 128) ? cnt[t] : 0;
    int lane = t & 63;
    int incl = v;
#pragma unroll
    for (int off = 1; off < 64; off <<= 1) {
        int u = __shfl_up(incl, off, 64);
        if (lane >= off) incl += u;
    }
    if (t == 63) s_w0 = incl;
    __syncthreads();
    if (t < 128) {
        int excl = incl - v + ((t >= 64) ? s_w0 : 0);
        int pos = bbase + excl;
        cur[t] = pos;
        int node = (b << BSHIFT) + t;
        if (node <= N) row_start[node] = pos;
    }
    __syncthreads();
    for (int i = t; i < c; i += 256) {
        unsigned e = buf[i];
        int pos = atomicAdd(&cur[(e >> 16) & 127], 1);
        sorted_src[pos] = (int)(e & 0xFFFFu);
    }
}

// ---------------- K2 path B: alpha1 ------------------------------------------
__device__ __forceinline__ void alpha1_body(
    int blk, const unsigned short* __restrict__ h1g,
    const float* __restrict__ a_s, const float* __restrict__ a_d,
    float* __restrict__ as_n, float* __restrict__ ad_n, int N) {
    int gid = blk * 256 + threadIdx.x;
    if (gid >= N * 8) return;
    int n = gid >> 3, hd = gid & 7;
    const uint4* hp = (const uint4*)(h1g + (size_t)n * 128 + hd * 16);
    uint4 u0 = hp[0], u1 = hp[1];
    unsigned uu[8] = {u0.x, u0.y, u0.z, u0.w, u1.x, u1.y, u1.z, u1.w};
    const float* sp = a_s + hd * 16;
    const float* dp = a_d + hd * 16;
    float s = 0.f, d = 0.f;
#pragma unroll
    for (int k = 0; k < 8; k++) {
        float lo = bf2f(uu[k] & 0xffffu), hi = bf2f(uu[k] >> 16);
        s += lo * sp[2 * k] + hi * sp[2 * k + 1];
        d += lo * dp[2 * k] + hi * dp[2 * k + 1];
    }
    as_n[gid] = s;
    ad_n[gid] = d;
}

__global__ __launch_bounds__(256) void k2_kernel(
    const int* __restrict__ gcursor, const unsigned* __restrict__ bucket_buf,
    int* __restrict__ row_start, int* __restrict__ sorted_src,
    const unsigned short* __restrict__ h1g,
    const float* __restrict__ a_s, const float* __restrict__ a_d,
    float* __restrict__ as_n, float* __restrict__ ad_n, int N, int NB) {
    if ((int)blockIdx.x < NB)
        bsort_body(blockIdx.x, gcursor, bucket_buf, row_start, sorted_src, N, NB);
    else
        alpha1_body(blockIdx.x - NB, h1g, a_s, a_d, as_n, ad_n, N);
}

// ---------------- layer-1 aggregation: wave/node, 8 edges/iter ---------------
__global__ __launch_bounds__(256) void agg1_kernel(
    const int* __restrict__ row_start, const int* __restrict__ sorted_src,
    const float* __restrict__ as_n, const float* __restrict__ ad_n,
    const unsigned short* __restrict__ h1g, const float* __restrict__ b1,
    unsigned short* __restrict__ h1act, int N) {
    int node = blockIdx.x * 4 + (threadIdx.x >> 6);
    int lane = threadIdx.x & 63;
    if (node >= N) return;
    int slot = lane >> 4, cg = lane & 15;
    int srcLane = (slot << 3) | (cg >> 1);     // weight source: slot*8 + head
    float ad_w = ad_n[node * 8 + (lane & 7)];
    int beg = row_start[node], end = row_start[node + 1];
    float acc[8];
#pragma unroll
    for (int k = 0; k < 8; k++) acc[k] = 0.f;
    float denom = 0.f;
    for (int i = beg; i < end; i += 8) {
        // two independent 4-edge groups for MLP
        int ewa = i + ((lane >> 3) & 3);
        int ewb = ewa + 4;
        int swa = sorted_src[min(ewa, end - 1)];
        int swb = sorted_src[min(ewb, end - 1)];
        float wa = __expf(lrelu(as_n[swa * 8 + (lane & 7)] + ad_w));
        float wb = __expf(lrelu(as_n[swb * 8 + (lane & 7)] + ad_w));
        wa = (ewa < end) ? wa : 0.f;
        wb = (ewb < end) ? wb : 0.f;
        float wva = __shfl(wa, srcLane, 64);
        float wvb = __shfl(wb, srcLane, 64);
        int ega = i + slot, egb = ega + 4;
        int sga = sorted_src[min(ega, end - 1)];
        int sgb = sorted_src[min(egb, end - 1)];
        uint4 hva = *(const uint4*)&h1g[(size_t)sga * 128 + cg * 8];
        uint4 hvb = *(const uint4*)&h1g[(size_t)sgb * 128 + cg * 8];
        acc[0] += wva * bf2f(hva.x & 0xffffu) + wvb * bf2f(hvb.x & 0xffffu);
        acc[1] += wva * bf2f(hva.x >> 16)     + wvb * bf2f(hvb.x >> 16);
        acc[2] += wva * bf2f(hva.y & 0xffffu) + wvb * bf2f(hvb.y & 0xffffu);
        acc[3] += wva * bf2f(hva.y >> 16)     + wvb * bf2f(hvb.y >> 16);
        acc[4] += wva * bf2f(hva.z & 0xffffu) + wvb * bf2f(hvb.z & 0xffffu);
        acc[5] += wva * bf2f(hva.z >> 16)     + wvb * bf2f(hvb.z >> 16);
        acc[6] += wva * bf2f(hva.w & 0xffffu) + wvb * bf2f(hvb.w & 0xffffu);
        acc[7] += wva * bf2f(hva.w >> 16)     + wvb * bf2f(hvb.w >> 16);
        denom += wva + wvb;
    }
    // reduce over the 4 slots (lanes differing in bits 4-5)
#pragma unroll
    for (int msk = 16; msk < 64; msk <<= 1) {
#pragma unroll
        for (int k = 0; k < 8; k++) acc[k] += __shfl_xor(acc[k], msk, 64);
        denom += __shfl_xor(denom, msk, 64);
    }
    if (slot == 0) {
        float inv = 1.f / (denom + 1e-16f);
        int c0 = cg * 8;
        unsigned ow[4];
#pragma unroll
        for (int p = 0; p < 4; p++) {
            float v0 = acc[2 * p] * inv + b1[c0 + 2 * p];
            float v1 = acc[2 * p + 1] * inv + b1[c0 + 2 * p + 1];
            v0 = (v0 > 0.f) ? v0 : (__expf(v0) - 1.f);
            v1 = (v1 > 0.f) ? v1 : (__expf(v1) - 1.f);
            ow[p] = (unsigned)f2bf(v0) | ((unsigned)f2bf(v1) << 16);
        }
        *(uint4*)&h1act[(size_t)node * 128 + c0] = make_uint4(ow[0], ow[1], ow[2], ow[3]);
    }
}

// ---------------- GEMM2 (MFMA) + fused alpha2 --------------------------------
__global__ __launch_bounds__(256) void gemm2_kernel(
    const unsigned short* __restrict__ h1act, const float* __restrict__ W2,
    const float* __restrict__ a_s, const float* __restrict__ a_d,
    unsigned short* __restrict__ h2g, float* __restrict__ as_n,
    float* __restrict__ ad_n, int N) {
    __shared__ short Wt[64 * 136];
    int t = threadIdx.x;
    for (int id = t; id < 128 * 16; id += 256) {
        int k = id >> 4;
        int n0 = (id & 15) * 4;
        float4 v = *(const float4*)&W2[k * 64 + n0];
        Wt[(n0 + 0) * 136 + k] = (short)f2bf(v.x);
        Wt[(n0 + 1) * 136 + k] = (short)f2bf(v.y);
        Wt[(n0 + 2) * 136 + k] = (short)f2bf(v.z);
        Wt[(n0 + 3) * 136 + k] = (short)f2bf(v.w);
    }
    __syncthreads();
    int wv = t >> 6, lane = t & 63;
    int m = lane & 15, q = lane >> 4;
    int row = blockIdx.x * 64 + wv * 16 + m;
    f32x4 acc[4];
#pragma unroll
    for (int j = 0; j < 4; j++) acc[j] = (f32x4){0.f, 0.f, 0.f, 0.f};
#pragma unroll
    for (int k0 = 0; k0 < 128; k0 += 32) {
        bf16x8 a = {0, 0, 0, 0, 0, 0, 0, 0};
        if (row < N) a = *(const bf16x8*)&h1act[(size_t)row * 128 + k0 + q * 8];
#pragma unroll
        for (int j = 0; j < 4; j++) {
            bf16x8 b = *(const bf16x8*)&Wt[(j * 16 + m) * 136 + k0 + q * 8];
            acc[j] = __builtin_amdgcn_mfma_f32_16x16x32_bf16(a, b, acc[j], 0, 0, 0);
        }
    }
    float asl[4], adl[4];
#pragma unroll
    for (int j = 0; j < 4; j++) { asl[j] = a_s[j * 16 + m]; adl[j] = a_d[j * 16 + m]; }
    int rbase = blockIdx.x * 64 + wv * 16 + q * 4;
#pragma unroll
    for (int r = 0; r < 4; r++) {
        int rr = rbase + r;
        float s = 0.f, d = 0.f;
#pragma unroll
        for (int j = 0; j < 4; j++) {
            s += acc[j][r] * asl[j];
            d += acc[j][r] * adl[j];
        }
#pragma unroll
        for (int msk = 8; msk > 0; msk >>= 1) {
            s += __shfl_xor(s, msk, 64);
            d += __shfl_xor(d, msk, 64);
        }
        if (rr < N) {
            if (m == 0) { as_n[rr] = s; ad_n[rr] = d; }
#pragma unroll
            for (int j = 0; j < 4; j++)
                h2g[(size_t)rr * 64 + j * 16 + m] = f2bf(acc[j][r]);
        }
    }
}

// ---------------- layer-2 aggregation + log_softmax: wave/node, 8 edges/iter -
__global__ __launch_bounds__(256) void agg2_kernel(
    const int* __restrict__ row_start, const int* __restrict__ sorted_src,
    const float* __restrict__ as_n, const float* __restrict__ ad_n,
    const unsigned short* __restrict__ h2g, const float* __restrict__ b2,
    float* __restrict__ out, int N) {
    int node = blockIdx.x * 4 + (threadIdx.x >> 6);
    int lane = threadIdx.x & 63;
    if (node >= N) return;
    int slot = lane >> 4, cg = lane & 15;
    float adv = ad_n[node];
    int beg = row_start[node], end = row_start[node + 1];
    float acc[4];
#pragma unroll
    for (int k = 0; k < 4; k++) acc[k] = 0.f;
    float denom = 0.f;
    for (int i = beg; i < end; i += 8) {
        int ewa = i + (lane & 3);
        int ewb = ewa + 4;
        int swa = sorted_src[min(ewa, end - 1)];
        int swb = sorted_src[min(ewb, end - 1)];
        float wa = __expf(lrelu(as_n[swa] + adv));
        float wb = __expf(lrelu(as_n[swb] + adv));
        wa = (ewa < end) ? wa : 0.f;
        wb = (ewb < end) ? wb : 0.f;
        float wva = __shfl(wa, slot, 64);
        float wvb = __shfl(wb, 4 + slot, 64);
        int ega = i + slot, egb = ega + 4;
        int sga = sorted_src[min(ega, end - 1)];
        int sgb = sorted_src[min(egb, end - 1)];
        uint2 hva = *(const uint2*)&h2g[(size_t)sga * 64 + cg * 4];
        uint2 hvb = *(const uint2*)&h2g[(size_t)sgb * 64 + cg * 4];
        acc[0] += wva * bf2f(hva.x & 0xffffu) + wvb * bf2f(hvb.x & 0xffffu);
        acc[1] += wva * bf2f(hva.x >> 16)     + wvb * bf2f(hvb.x >> 16);
        acc[2] += wva * bf2f(hva.y & 0xffffu) + wvb * bf2f(hvb.y & 0xffffu);
        acc[3] += wva * bf2f(hva.y >> 16)     + wvb * bf2f(hvb.y >> 16);
        denom += wva + wvb;
    }
#pragma unroll
    for (int msk = 16; msk < 64; msk <<= 1) {
#pragma unroll
        for (int k = 0; k < 4; k++) acc[k] += __shfl_xor(acc[k], msk, 64);
        denom += __shfl_xor(denom, msk, 64);
    }
    if (slot == 0) {
        float inv = 1.f / (denom + 1e-16f);
        int c0 = cg * 4;
        float v[4];
#pragma unroll
        for (int k = 0; k < 4; k++) v[k] = acc[k] * inv + b2[c0 + k];
        float m = fmaxf(fmaxf(v[0], v[1]), fmaxf(v[2], v[3]));
#pragma unroll
        for (int msk = 8; msk > 0; msk >>= 1) m = fmaxf(m, __shfl_xor(m, msk, 64));
        float ex = __expf(v[0] - m) + __expf(v[1] - m) + __expf(v[2] - m) + __expf(v[3] - m);
#pragma unroll
        for (int msk = 8; msk > 0; msk >>= 1) ex += __shfl_xor(ex, msk, 64);
        float lse = m + __logf(ex);
        float4 ov = make_float4(v[0] - lse, v[1] - lse, v[2] - lse, v[3] - lse);
        *(float4*)&out[(size_t)node * 64 + c0] = ov;
    }
}

extern "C" void kernel_launch(void* const* d_in, const int* in_sizes, int n_in,
                              void* d_out, int out_size, void* d_ws, size_t ws_size,
                              hipStream_t stream) {
    const float* x   = (const float*)d_in[0];
    const int*   idx = (const int*)d_in[1];
    const float* W1  = (const float*)d_in[2];
    const float* as1 = (const float*)d_in[3];
    const float* ad1 = (const float*)d_in[4];
    const float* b1  = (const float*)d_in[5];
    const float* W2  = (const float*)d_in[6];
    const float* as2 = (const float*)d_in[7];
    const float* ad2 = (const float*)d_in[8];
    const float* b2  = (const float*)d_in[9];
    float* out = (float*)d_out;

    const int N = in_sizes[0] / IN_DIM;
    const int E = in_sizes[1] / 2;
    const int EN = E + N;
    const int NB = (N + (1 << BSHIFT) - 1) >> BSHIFT;   // buckets
    const int GS = (EN + 256 * EPT - 1) / (256 * EPT);  // bscatter blocks
    const int G1 = (N + 63) / 64;                        // gemm1 blocks
    const int A1 = (N * 8 + 255) / 256;                  // alpha1 blocks

    // workspace layout
    unsigned short* h1g   = (unsigned short*)d_ws;          // N*128 bf16
    unsigned short* h1act = h1g + (size_t)N * 128;          // N*128 bf16
    unsigned short* h2g   = h1act + (size_t)N * 128;        // N*64 bf16
    float* as1n = (float*)(h2g + (size_t)N * 64);           // N*8
    float* ad1n = as1n + (size_t)N * 8;                     // N*8
    float* as2n = ad1n + (size_t)N * 8;                     // N
    float* ad2n = as2n + (size_t)N;                         // N
    int* row_start  = (int*)(ad2n + (size_t)N);             // N+1
    int* gcursor    = row_start + N + 1;                    // 512
    unsigned* bucket_buf = (unsigned*)(gcursor + 512);      // NB*BCAP
    int* sorted_src = (int*)(bucket_buf + ((size_t)NB << BCAPSHIFT));  // E+N
    (void)ws_size; (void)n_in; (void)out_size;

    hipMemsetAsync(gcursor, 0, 512 * sizeof(int), stream);

    k1_kernel<<<GS + G1, 256, 0, stream>>>(idx, gcursor, bucket_buf,
                                           x, W1, h1g, E, N, NB, GS);
    k2_kernel<<<NB + A1, 256, 0, stream>>>(gcursor, bucket_buf, row_start, sorted_src,
                                           h1g, as1, ad1, as1n, ad1n, N, NB);
    agg1_kernel<<<(N + 3) / 4, 256, 0, stream>>>(row_start, sorted_src, as1n, ad1n, h1g, b1, h1act, N);
    gemm2_kernel<<<(N + 63) / 64, 256, 0, stream>>>(h1act, W2, as2, ad2, h2g, as2n, ad2n, N);
    agg2_kernel<<<(N + 3) / 4, 256, 0, stream>>>(row_start, sorted_src, as2n, ad2n, h2g, b2, out, N);
}